// Round 2
// baseline (2969.610 us; speedup 1.0000x reference)
//
#include <hip/hip_runtime.h>
#include <hip/hip_bf16.h>

// Problem constants (from reference)
#define NN   50000
#define EE   1600000
#define INC  128
#define HH   64
#define OUTC 40
#define ALPHA 0.8f
#define LN_EPS 1e-5f
// h is stored pre-scaled by 2*log2(e) so tanh needs no per-edge multiply:
// tanh(x) = 1 - 2/(1 + 2^(KTANH*x))
#define KTANH 2.8853900817779268f

// ---------------------------------------------------------------------------
// Raw buffer ops. Gather: soffset = SALU row byte-offset (wave-uniform),
// voffset = lane*4 -> ZERO VALU addressing. Atomic fadd likewise.
// ---------------------------------------------------------------------------
typedef int v4i_t __attribute__((ext_vector_type(4)));
__device__ float llvm_amdgcn_raw_buffer_load_fp32(v4i_t srsrc, int voffset,
                                                  int soffset, int glc_slc)
    __asm("llvm.amdgcn.raw.buffer.load.f32");
__device__ float llvm_amdgcn_raw_buffer_atomic_fadd_f32(float vdata, v4i_t srsrc,
                                                        int voffset, int soffset,
                                                        int slc)
    __asm("llvm.amdgcn.raw.buffer.atomic.fadd.f32");

// ---------------------------------------------------------------------------
// Wave64 sum via fused v_add_f32_dpp (inline asm; 1 inst/stage guaranteed).
// 8 independent chains interleaved (also satisfies DPP wait-states).
// Total lands in lane 63. Stage 1 writes FRESH dests for s0..s3 (reads
// d0..d3 directly) so the d values survive without v_mov copies.
// ---------------------------------------------------------------------------
#define DPP8(CTRL)                                                             \
    asm volatile(                                                              \
        "v_add_f32_dpp %0, %0, %0 " CTRL "\n\t"                                \
        "v_add_f32_dpp %1, %1, %1 " CTRL "\n\t"                                \
        "v_add_f32_dpp %2, %2, %2 " CTRL "\n\t"                                \
        "v_add_f32_dpp %3, %3, %3 " CTRL "\n\t"                                \
        "v_add_f32_dpp %4, %4, %4 " CTRL "\n\t"                                \
        "v_add_f32_dpp %5, %5, %5 " CTRL "\n\t"                                \
        "v_add_f32_dpp %6, %6, %6 " CTRL "\n\t"                                \
        "v_add_f32_dpp %7, %7, %7 " CTRL                                       \
        : "+v"(s0), "+v"(s1), "+v"(s2), "+v"(s3),                              \
          "+v"(s4), "+v"(s5), "+v"(s6), "+v"(s7))

#define DPP8_FIRST(CTRL)                                                       \
    asm volatile(                                                              \
        "v_add_f32_dpp %0, %8, %8 " CTRL "\n\t"                                \
        "v_add_f32_dpp %1, %9, %9 " CTRL "\n\t"                                \
        "v_add_f32_dpp %2, %10, %10 " CTRL "\n\t"                              \
        "v_add_f32_dpp %3, %11, %11 " CTRL "\n\t"                              \
        "v_add_f32_dpp %4, %4, %4 " CTRL "\n\t"                                \
        "v_add_f32_dpp %5, %5, %5 " CTRL "\n\t"                                \
        "v_add_f32_dpp %6, %6, %6 " CTRL "\n\t"                                \
        "v_add_f32_dpp %7, %7, %7 " CTRL                                       \
        : "=&v"(s0), "=&v"(s1), "=&v"(s2), "=&v"(s3),                          \
          "+v"(s4), "+v"(s5), "+v"(s6), "+v"(s7)                               \
        : "v"(d0), "v"(d1), "v"(d2), "v"(d3))

#define DPP_ALL6()                                                             \
    DPP8_FIRST("row_shr:1 row_mask:0xf bank_mask:0xf bound_ctrl:0");           \
    DPP8("row_shr:2 row_mask:0xf bank_mask:0xf bound_ctrl:0");                 \
    DPP8("row_shr:4 row_mask:0xf bank_mask:0xf bound_ctrl:0");                 \
    DPP8("row_shr:8 row_mask:0xf bank_mask:0xf bound_ctrl:0");                 \
    DPP8("row_bcast:15 row_mask:0xa bank_mask:0xf bound_ctrl:0");              \
    DPP8("row_bcast:31 row_mask:0xc bank_mask:0xf bound_ctrl:0")

__device__ __forceinline__ float rl63(float x) {
    return __int_as_float(__builtin_amdgcn_readlane(__float_as_int(x), 63));
}

// input already pre-scaled by KTANH: tanh = 1 - 2/(1 + 2^xs)
__device__ __forceinline__ float fast_tanh_pre(float xs) {
    float e = __builtin_amdgcn_exp2f(xs);
    float u = __builtin_amdgcn_rcpf(1.0f + e);
    return __builtin_fmaf(-2.0f, u, 1.0f);
}

// ---------------------------------------------------------------------------
// G = W @ W^T  (64x64). One block.
// ---------------------------------------------------------------------------
__global__ __launch_bounds__(256) void make_G(const float* __restrict__ W,
                                              float* __restrict__ G) {
    __shared__ float Ws[64 * 64];
    for (int t = threadIdx.x; t < 64 * 64; t += 256) Ws[t] = W[t];
    __syncthreads();
    for (int t = threadIdx.x; t < 64 * 64; t += 256) {
        int i = t >> 6, j = t & 63;
        float acc = 0.f;
#pragma unroll 8
        for (int k = 0; k < 64; ++k) acc += Ws[i * 64 + k] * Ws[j * 64 + k];
        G[t] = acc;
    }
}

// ---------------------------------------------------------------------------
// extractor: xh = x@We^T + be ; h0 = KTANH*(xh@U^T + bU) ; xU = (xh@U^T+bU)/nf
// ---------------------------------------------------------------------------
__global__ __launch_bounds__(256) void extractor(
        const float* __restrict__ x, const float* __restrict__ nf,
        const float* __restrict__ We, const float* __restrict__ be,
        const float* __restrict__ U,  const float* __restrict__ bU,
        float* __restrict__ xh, float* __restrict__ xU, float* __restrict__ h0) {
    __shared__ float WeT[INC * HH];
    __shared__ float UT[HH * HH];
    __shared__ float beS[HH], bUS[HH];
    __shared__ float xs[4][INC];
    __shared__ float xhs[4][HH];

    for (int t = threadIdx.x; t < INC * HH; t += 256) {
        int j = t >> 7, k = t & 127;
        WeT[k * 64 + j] = We[t];
    }
    for (int t = threadIdx.x; t < HH * HH; t += 256) {
        int j = t >> 6, k = t & 63;
        UT[k * 64 + j] = U[t];
    }
    if (threadIdx.x < 64) { beS[threadIdx.x] = be[threadIdx.x]; bUS[threadIdx.x] = bU[threadIdx.x]; }
    __syncthreads();

    int lane = threadIdx.x & 63;
    int wv   = threadIdx.x >> 6;

    for (int n0 = blockIdx.x * 4; n0 < NN; n0 += gridDim.x * 4) {
        int n = n0 + wv;
        bool valid = n < NN;
        if (valid) {
            xs[wv][lane]      = x[(size_t)n * INC + lane];
            xs[wv][lane + 64] = x[(size_t)n * INC + lane + 64];
        }
        __syncthreads();
        float acc = beS[lane];
        if (valid) {
#pragma unroll 8
            for (int k = 0; k < INC; ++k) acc += xs[wv][k] * WeT[k * 64 + lane];
            xh[n * 64 + lane] = acc;
            xhs[wv][lane] = acc;
        }
        __syncthreads();
        if (valid) {
            float acc2 = bUS[lane];
#pragma unroll 8
            for (int k = 0; k < HH; ++k) acc2 += xhs[wv][k] * UT[k * 64 + lane];
            h0[n * 64 + lane] = KTANH * acc2;
            xU[n * 64 + lane] = acc2 / nf[n];
        }
        __syncthreads();
    }
}

// ---------------------------------------------------------------------------
// edge_pass (R13): edge-centric half-work step. Each quad of 4 undirected
// edges: gather h[row],h[col], tanh once, LN stats once, then scatter
// +-(gamma*rsig*(d-mu)+beta) to both endpoints via buffer_atomic_add_f32.
// gamma/beta folded per edge; sigma machinery eliminated. No CSR needed.
// ---------------------------------------------------------------------------
__global__ __launch_bounds__(256) void edge_pass(
        const int* __restrict__ ei, const float* __restrict__ hcur,
        const float* __restrict__ gamma, const float* __restrict__ beta,
        float* __restrict__ acc) {
    const int lane = threadIdx.x & 63, wv = threadIdx.x >> 6;
    const float g  = gamma[lane];
    const float bp = beta[lane];
    const float bn = -bp;

    v4i_t hsr, asr;
    {
        unsigned long long up = (unsigned long long)(uintptr_t)hcur;
        hsr.x = (int)(unsigned)(up & 0xffffffffull);
        hsr.y = (int)(unsigned)(up >> 32);
        hsr.z = NN * HH * 4;
        hsr.w = 0x00020000;
    }
    {
        unsigned long long up = (unsigned long long)(uintptr_t)acc;
        asr.x = (int)(unsigned)(up & 0xffffffffull);
        asr.y = (int)(unsigned)(up >> 32);
        asr.z = NN * HH * 4;
        asr.w = 0x00020000;
    }
    const int lane4 = lane << 2;
#define GATH(so) llvm_amdgcn_raw_buffer_load_fp32(hsr, lane4, (so), 0)
#define FADD(v, so) (void)llvm_amdgcn_raw_buffer_atomic_fadd_f32((v), asr, lane4, (so), 0)

    const int NW = 2048 * 4;      // total waves
    const int NQ = EE >> 2;       // 400000 quads, no remainder

    int qcur = blockIdx.x * 4 + wv;
    if (qcur >= NQ) return;

    // prologue: uv + gathers for qcur, uv for qcur+NW
    int q0 = __builtin_amdgcn_readfirstlane(qcur);
    int4 uu = *(const int4*)(ei + 4 * q0);
    int4 vv = *(const int4*)(ei + EE + 4 * q0);
    int su0 = uu.x << 8, su1 = uu.y << 8, su2 = uu.z << 8, su3 = uu.w << 8;
    int sv0 = vv.x << 8, sv1 = vv.y << 8, sv2 = vv.z << 8, sv3 = vv.w << 8;
    float hu0 = GATH(su0), hu1 = GATH(su1), hu2 = GATH(su2), hu3 = GATH(su3);
    float hv0 = GATH(sv0), hv1 = GATH(sv1), hv2 = GATH(sv2), hv3 = GATH(sv3);

    int qn = qcur + NW;
    int4 uun = uu, vvn = vv;
    if (qn < NQ) {
        int qs = __builtin_amdgcn_readfirstlane(qn);
        uun = *(const int4*)(ei + 4 * qs);
        vvn = *(const int4*)(ei + EE + 4 * qs);
    }

    for (;;) {
        const bool more = (qn < NQ);
        // prefetch uv two quads ahead (hides SMEM latency behind this quad)
        const int qn2 = qn + NW;
        int4 uu2 = uun, vv2 = vvn;
        if (qn2 < NQ) {
            int qs2 = __builtin_amdgcn_readfirstlane(qn2);
            uu2 = *(const int4*)(ei + 4 * qs2);
            vv2 = *(const int4*)(ei + EE + 4 * qs2);
        }
        // issue next quad's 8 gathers (latency hidden under current compute)
        int tu0, tu1, tu2, tu3, tv0, tv1, tv2, tv3;
        float pu0, pu1, pu2, pu3, pv0, pv1, pv2, pv3;
        if (more) {
            tu0 = uun.x << 8; tu1 = uun.y << 8; tu2 = uun.z << 8; tu3 = uun.w << 8;
            tv0 = vvn.x << 8; tv1 = vvn.y << 8; tv2 = vvn.z << 8; tv3 = vvn.w << 8;
            pu0 = GATH(tu0); pu1 = GATH(tu1); pu2 = GATH(tu2); pu3 = GATH(tu3);
            pv0 = GATH(tv0); pv1 = GATH(tv1); pv2 = GATH(tv2); pv3 = GATH(tv3);
        }

        // ---- current quad: d = tanh once per undirected edge
        float d0 = fast_tanh_pre(hu0 - hv0);
        float d1 = fast_tanh_pre(hu1 - hv1);
        float d2 = fast_tanh_pre(hu2 - hv2);
        float d3 = fast_tanh_pre(hu3 - hv3);
        float s0, s1, s2, s3;
        float s4 = d0 * d0, s5 = d1 * d1, s6 = d2 * d2, s7 = d3 * d3;
        DPP_ALL6();
        float t10 = rl63(s0), t11 = rl63(s1), t12 = rl63(s2), t13 = rl63(s3);
        float t20 = rl63(s4), t21 = rl63(s5), t22 = rl63(s6), t23 = rl63(s7);

        // LN per edge + dual scatter. var >= ~9.9e-6 always (eps folded).
        {
            float mu   = t10 * 0.015625f;
            float var  = __builtin_fmaf(t20, 0.015625f, __builtin_fmaf(-mu, mu, LN_EPS));
            float rsig = __frsqrt_rn(var);
            float c2   = -rsig * mu;
            float inner = __builtin_fmaf(d0, rsig, c2);
            float rowv  = __builtin_fmaf(g, inner, bp);
            float colv  = __builtin_fmaf(g, -inner, bn);
            FADD(rowv, su0); FADD(colv, sv0);
        }
        {
            float mu   = t11 * 0.015625f;
            float var  = __builtin_fmaf(t21, 0.015625f, __builtin_fmaf(-mu, mu, LN_EPS));
            float rsig = __frsqrt_rn(var);
            float c2   = -rsig * mu;
            float inner = __builtin_fmaf(d1, rsig, c2);
            float rowv  = __builtin_fmaf(g, inner, bp);
            float colv  = __builtin_fmaf(g, -inner, bn);
            FADD(rowv, su1); FADD(colv, sv1);
        }
        {
            float mu   = t12 * 0.015625f;
            float var  = __builtin_fmaf(t22, 0.015625f, __builtin_fmaf(-mu, mu, LN_EPS));
            float rsig = __frsqrt_rn(var);
            float c2   = -rsig * mu;
            float inner = __builtin_fmaf(d2, rsig, c2);
            float rowv  = __builtin_fmaf(g, inner, bp);
            float colv  = __builtin_fmaf(g, -inner, bn);
            FADD(rowv, su2); FADD(colv, sv2);
        }
        {
            float mu   = t13 * 0.015625f;
            float var  = __builtin_fmaf(t23, 0.015625f, __builtin_fmaf(-mu, mu, LN_EPS));
            float rsig = __frsqrt_rn(var);
            float c2   = -rsig * mu;
            float inner = __builtin_fmaf(d3, rsig, c2);
            float rowv  = __builtin_fmaf(g, inner, bp);
            float colv  = __builtin_fmaf(g, -inner, bn);
            FADD(rowv, su3); FADD(colv, sv3);
        }

        if (!more) break;
        su0 = tu0; su1 = tu1; su2 = tu2; su3 = tu3;
        sv0 = tv0; sv1 = tv1; sv2 = tv2; sv3 = tv3;
        hu0 = pu0; hu1 = pu1; hu2 = pu2; hu3 = pu3;
        hv0 = pv0; hv1 = pv1; hv2 = pv2; hv3 = pv3;
        uun = uu2; vvn = vv2;
        qn = qn2;
    }
#undef GATH
#undef FADD
}

// ---------------------------------------------------------------------------
// node_pass: av = nf*acc (gamma/beta already folded in edge_pass);
// p = G-matvec; y/s updates; hnxt = KTANH*nf*(y + xU); re-zero acc.
// ---------------------------------------------------------------------------
__global__ __launch_bounds__(256) void node_pass(
        float* __restrict__ acc, const float* __restrict__ nf,
        const float* __restrict__ Gm, const float* __restrict__ xU,
        float* __restrict__ hnxt, float* __restrict__ y, float* __restrict__ s,
        int first, int last) {
    __shared__ float Gs[64 * 64];
    for (int t = threadIdx.x; t < 64 * 64; t += 256) Gs[t] = Gm[t];
    __syncthreads();

    const int lane = threadIdx.x & 63, wv = threadIdx.x >> 6;
    for (int n = blockIdx.x * 4 + wv; n < NN; n += gridDim.x * 4) {
        const float nfn = nf[n];
        const float av  = nfn * acc[(size_t)n * 64 + lane];
        acc[(size_t)n * 64 + lane] = 0.f;   // ready for next step's atomics

        float p = 0.f;
        const int avi = __float_as_int(av);
#pragma unroll
        for (int k = 0; k < 64; ++k) {
            float ak = __int_as_float(__builtin_amdgcn_readlane(avi, k));
            p = __builtin_fmaf(ak, Gs[k * 64 + lane], p);
        }

        float yprev = 0.f, sprev = 0.f;
        if (!first) {
            yprev = y[n * 64 + lane];
            sprev = s[n * 64 + lane];
        }
        const float yv = -ALPHA * p + (1.0f - ALPHA) * yprev;
        y[n * 64 + lane] = yv;
        s[n * 64 + lane] = (1.0f - ALPHA) * sprev + av;
        if (!last) hnxt[n * 64 + lane] = KTANH * (nfn * (yv + xU[n * 64 + lane]));
    }
}

// ---------------------------------------------------------------------------
// final: z = -alpha*(s@W) ; zf = nf*z + xh ; out = zf@Wlast^T + blast
// ---------------------------------------------------------------------------
__global__ __launch_bounds__(256) void final_out(
        const float* __restrict__ s, const float* __restrict__ xh,
        const float* __restrict__ nf, const float* __restrict__ W,
        const float* __restrict__ Wlast, const float* __restrict__ blast,
        float* __restrict__ out) {
    __shared__ float Ws[64 * 64];
    __shared__ float WlT[64 * OUTC];
    __shared__ float blS[OUTC];
    __shared__ float ss[4][64];
    __shared__ float zfs[4][64];
    for (int t = threadIdx.x; t < 64 * 64; t += 256) Ws[t] = W[t];
    for (int t = threadIdx.x; t < OUTC * 64; t += 256) {
        int o = t >> 6, j = t & 63;
        WlT[j * OUTC + o] = Wlast[t];
    }
    if (threadIdx.x < OUTC) blS[threadIdx.x] = blast[threadIdx.x];
    __syncthreads();
    int lane = threadIdx.x & 63, wv = threadIdx.x >> 6;
    for (int n0 = blockIdx.x * 4; n0 < NN; n0 += gridDim.x * 4) {
        int n = n0 + wv;
        if (n < NN) ss[wv][lane] = s[n * 64 + lane];
        __syncthreads();
        if (n < NN) {
            float z = 0.f;
#pragma unroll 8
            for (int k = 0; k < 64; ++k) z += ss[wv][k] * Ws[k * 64 + lane];
            z *= -ALPHA;
            zfs[wv][lane] = nf[n] * z + xh[n * 64 + lane];
        }
        __syncthreads();
        if (n < NN && lane < OUTC) {
            float acc = blS[lane];
#pragma unroll 8
            for (int j = 0; j < 64; ++j) acc += zfs[wv][j] * WlT[j * OUTC + lane];
            out[n * OUTC + lane] = acc;
        }
        __syncthreads();
    }
}

// ---------------------------------------------------------------------------
extern "C" void kernel_launch(void* const* d_in, const int* in_sizes, int n_in,
                              void* d_out, int out_size, void* d_ws, size_t ws_size,
                              hipStream_t stream) {
    const float* x     = (const float*)d_in[0];
    const int*   ei    = (const int*)  d_in[1];
    const float* nf    = (const float*)d_in[2];
    const float* We    = (const float*)d_in[3];
    const float* be    = (const float*)d_in[4];
    const float* W     = (const float*)d_in[5];
    const float* U     = (const float*)d_in[6];
    const float* bU    = (const float*)d_in[7];
    const float* gamma = (const float*)d_in[8];
    const float* beta  = (const float*)d_in[9];
    const float* Wlast = (const float*)d_in[10];
    const float* blast = (const float*)d_in[11];
    float* out = (float*)d_out;

    char* ws = (char*)d_ws;
    size_t off = 0;
    const size_t NH = (size_t)NN * HH * sizeof(float);
    float* acc    = (float*)(ws + off);          off += NH;
    float* xh     = (float*)(ws + off);          off += NH;
    float* xU     = (float*)(ws + off);          off += NH;
    float* h0     = (float*)(ws + off);          off += NH;
    float* h1     = (float*)(ws + off);          off += NH;
    float* y      = (float*)(ws + off);          off += NH;
    float* s      = (float*)(ws + off);          off += NH;
    float* G      = (float*)(ws + off);          off += (size_t)HH * HH * sizeof(float);

    // acc must be zero before the first edge_pass; node_pass re-zeroes it
    // for subsequent steps.
    hipMemsetAsync(acc, 0, NH, stream);

    make_G<<<1, 256, 0, stream>>>(W, G);
    extractor<<<2048, 256, 0, stream>>>(x, nf, We, be, U, bU, xh, xU, h0);

    float* hc = h0;
    float* hn = h1;
    for (int t = 0; t < 4; ++t) {
        edge_pass<<<2048, 256, 0, stream>>>(ei, hc, gamma, beta, acc);
        node_pass<<<2048, 256, 0, stream>>>(acc, nf, G, xU, hn, y, s,
                                            t == 0, t == 3);
        float* tmp = hc; hc = hn; hn = tmp;
    }
    final_out<<<2048, 256, 0, stream>>>(s, xh, nf, W, Wlast, blast, out);
}

// Round 3
// 1326.330 us; speedup vs baseline: 2.2390x; 2.2390x over previous
//
#include <hip/hip_runtime.h>
#include <hip/hip_bf16.h>

// Problem constants (from reference)
#define NN   50000
#define EE   1600000
#define INC  128
#define HH   64
#define OUTC 40
#define ALPHA 0.8f
#define LN_EPS 1e-5f
#define NB_SCAN 196   // ceil(NN/256)
// h is stored pre-scaled by 2*log2(e) so tanh needs no per-edge multiply:
// tanh(x) = 1 - 2/(1 + 2^(KTANH*x))
#define KTANH 2.8853900817779268f

// ---------------------------------------------------------------------------
// Raw buffer load. Gather: soffset = SALU row byte-offset (wave-uniform),
// voffset = lane*4 -> ZERO VALU addressing.
// ---------------------------------------------------------------------------
typedef int v4i_t __attribute__((ext_vector_type(4)));
__device__ float llvm_amdgcn_raw_buffer_load_fp32(v4i_t srsrc, int voffset,
                                                  int soffset, int glc_slc)
    __asm("llvm.amdgcn.raw.buffer.load.f32");

// ---------------------------------------------------------------------------
// Wave64 sum via fused v_add_f32_dpp (inline asm; 1 inst/stage guaranteed).
// 8 independent chains interleaved (also satisfies DPP wait-states).
// Total lands in lane 63. Stage 1 writes FRESH dests for s0..s3 (reads
// d0..d3 directly) so the d values survive without v_mov copies.
// ---------------------------------------------------------------------------
#define DPP8(CTRL)                                                             \
    asm volatile(                                                              \
        "v_add_f32_dpp %0, %0, %0 " CTRL "\n\t"                                \
        "v_add_f32_dpp %1, %1, %1 " CTRL "\n\t"                                \
        "v_add_f32_dpp %2, %2, %2 " CTRL "\n\t"                                \
        "v_add_f32_dpp %3, %3, %3 " CTRL "\n\t"                                \
        "v_add_f32_dpp %4, %4, %4 " CTRL "\n\t"                                \
        "v_add_f32_dpp %5, %5, %5 " CTRL "\n\t"                                \
        "v_add_f32_dpp %6, %6, %6 " CTRL "\n\t"                                \
        "v_add_f32_dpp %7, %7, %7 " CTRL                                       \
        : "+v"(s0), "+v"(s1), "+v"(s2), "+v"(s3),                              \
          "+v"(s4), "+v"(s5), "+v"(s6), "+v"(s7))

#define DPP8_FIRST(CTRL)                                                       \
    asm volatile(                                                              \
        "v_add_f32_dpp %0, %8, %8 " CTRL "\n\t"                                \
        "v_add_f32_dpp %1, %9, %9 " CTRL "\n\t"                                \
        "v_add_f32_dpp %2, %10, %10 " CTRL "\n\t"                              \
        "v_add_f32_dpp %3, %11, %11 " CTRL "\n\t"                              \
        "v_add_f32_dpp %4, %4, %4 " CTRL "\n\t"                                \
        "v_add_f32_dpp %5, %5, %5 " CTRL "\n\t"                                \
        "v_add_f32_dpp %6, %6, %6 " CTRL "\n\t"                                \
        "v_add_f32_dpp %7, %7, %7 " CTRL                                       \
        : "=&v"(s0), "=&v"(s1), "=&v"(s2), "=&v"(s3),                          \
          "+v"(s4), "+v"(s5), "+v"(s6), "+v"(s7)                               \
        : "v"(d0), "v"(d1), "v"(d2), "v"(d3))

#define DPP_ALL6()                                                             \
    DPP8_FIRST("row_shr:1 row_mask:0xf bank_mask:0xf bound_ctrl:0");           \
    DPP8("row_shr:2 row_mask:0xf bank_mask:0xf bound_ctrl:0");                 \
    DPP8("row_shr:4 row_mask:0xf bank_mask:0xf bound_ctrl:0");                 \
    DPP8("row_shr:8 row_mask:0xf bank_mask:0xf bound_ctrl:0");                 \
    DPP8("row_bcast:15 row_mask:0xa bank_mask:0xf bound_ctrl:0");              \
    DPP8("row_bcast:31 row_mask:0xc bank_mask:0xf bound_ctrl:0")

__device__ __forceinline__ float rl63(float x) {
    return __int_as_float(__builtin_amdgcn_readlane(__float_as_int(x), 63));
}

// input already pre-scaled by KTANH: tanh = 1 - 2/(1 + 2^xs)
__device__ __forceinline__ float fast_tanh_pre(float xs) {
    float e = __builtin_amdgcn_exp2f(xs);
    float u = __builtin_amdgcn_rcpf(1.0f + e);
    return __builtin_fmaf(-2.0f, u, 1.0f);
}

// one quad (4 edges): returns sum_i rsig_i*(d_i-mu_i).
// GUARD=true applies the tail-validity mask (j0+i < nv). Garbage d values
// from invalid lanes are finite (bounds-checked loads return 0) and their
// contribution is zeroed via rsig=0, so no index clamping is needed.
template <bool GUARD>
__device__ __forceinline__ float quad_contrib(float hn, float hv0, float hv1,
                                              float hv2, float hv3,
                                              int j0, int nv) {
    float d0 = fast_tanh_pre(hn - hv0);
    float d1 = fast_tanh_pre(hn - hv1);
    float d2 = fast_tanh_pre(hn - hv2);
    float d3 = fast_tanh_pre(hn - hv3);
    float s0, s1, s2, s3;
    float s4 = d0 * d0, s5 = d1 * d1, s6 = d2 * d2, s7 = d3 * d3;
    DPP_ALL6();
    float t10 = rl63(s0), t11 = rl63(s1), t12 = rl63(s2), t13 = rl63(s3);
    float t20 = rl63(s4), t21 = rl63(s5), t22 = rl63(s6), t23 = rl63(s7);

    float acc = 0.f, mu, var, rsig;
    // var+eps folded: v = fma(t2,1/64, fma(-mu,mu,eps)).
    // (sum d)^2 <= 64*sum d^2 (Cauchy-Schwarz) so var >= ~9.9e-6 always.
    mu  = t10 * 0.015625f;
    var = __builtin_fmaf(t20, 0.015625f, __builtin_fmaf(-mu, mu, LN_EPS));
    rsig = __frsqrt_rn(var);
    if (GUARD) rsig = (j0 + 0 < nv) ? rsig : 0.f;
    acc = __builtin_fmaf(rsig, d0 - mu, acc);

    mu  = t11 * 0.015625f;
    var = __builtin_fmaf(t21, 0.015625f, __builtin_fmaf(-mu, mu, LN_EPS));
    rsig = __frsqrt_rn(var);
    if (GUARD) rsig = (j0 + 1 < nv) ? rsig : 0.f;
    acc = __builtin_fmaf(rsig, d1 - mu, acc);

    mu  = t12 * 0.015625f;
    var = __builtin_fmaf(t22, 0.015625f, __builtin_fmaf(-mu, mu, LN_EPS));
    rsig = __frsqrt_rn(var);
    if (GUARD) rsig = (j0 + 2 < nv) ? rsig : 0.f;
    acc = __builtin_fmaf(rsig, d2 - mu, acc);

    mu  = t13 * 0.015625f;
    var = __builtin_fmaf(t23, 0.015625f, __builtin_fmaf(-mu, mu, LN_EPS));
    rsig = __frsqrt_rn(var);
    if (GUARD) rsig = (j0 + 3 < nv) ? rsig : 0.f;
    acc = __builtin_fmaf(rsig, d3 - mu, acc);
    return acc;
}

// ---------------------------------------------------------------------------
// CSR build, atomic-light: count returns per-node rank; fill is
// atomic-free scattered stores (L2-absorbed).
// adj entry encoding: (other<<8) | (role<<31)
//   bits [23:8] = other node id * 256 = byte offset of its h row
//   bit 31      = role (1 if this incidence sees the node as col -> sign -1)
// ---------------------------------------------------------------------------
__global__ __launch_bounds__(256) void csr_count(const int* __restrict__ ei,
                                                 int* __restrict__ cnt,
                                                 unsigned short* __restrict__ rank16) {
    int i = blockIdx.x * 256 + threadIdx.x;
    if (i >= 2 * EE) return;
    int r = atomicAdd(&cnt[ei[i]], 1);
    rank16[i] = (unsigned short)r;
}

__global__ __launch_bounds__(256) void scanA(const int* __restrict__ cnt,
                                             int* __restrict__ offs,
                                             int* __restrict__ bsum) {
    __shared__ int tmp[256];
    int i = blockIdx.x * 256 + threadIdx.x;
    int v = (i < NN) ? cnt[i] : 0;
    tmp[threadIdx.x] = v;
    __syncthreads();
    int acc = v;
    for (int d = 1; d < 256; d <<= 1) {
        int t = (threadIdx.x >= d) ? tmp[threadIdx.x - d] : 0;
        __syncthreads();
        acc += t;
        tmp[threadIdx.x] = acc;
        __syncthreads();
    }
    if (i < NN) offs[i] = acc - v;
    if (threadIdx.x == 255) bsum[blockIdx.x] = acc;
}

__global__ __launch_bounds__(256) void scanB(int* __restrict__ bsum) {
    __shared__ int tmp[256];
    int v = (threadIdx.x < NB_SCAN) ? bsum[threadIdx.x] : 0;
    tmp[threadIdx.x] = v;
    __syncthreads();
    int acc = v;
    for (int d = 1; d < 256; d <<= 1) {
        int t = (threadIdx.x >= d) ? tmp[threadIdx.x - d] : 0;
        __syncthreads();
        acc += t;
        tmp[threadIdx.x] = acc;
        __syncthreads();
    }
    if (threadIdx.x < NB_SCAN) bsum[threadIdx.x] = acc - v;
}

__global__ __launch_bounds__(256) void scanC(int* __restrict__ offs,
                                             const int* __restrict__ bsum) {
    int i = blockIdx.x * 256 + threadIdx.x;
    if (i < NN) offs[i] += bsum[blockIdx.x];
}

__global__ __launch_bounds__(256) void csr_fill(const int* __restrict__ ei,
                                                const int* __restrict__ offs,
                                                const unsigned short* __restrict__ rank16,
                                                int* __restrict__ adj) {
    int i = blockIdx.x * 256 + threadIdx.x;
    if (i >= 2 * EE) return;
    int node  = ei[i];
    int role  = (i >= EE) ? 1 : 0;
    int other = role ? ei[i - EE] : ei[i + EE];
    adj[offs[node] + (int)rank16[i]] =
        (int)(((unsigned)other << 8) | ((unsigned)role << 31));
}

// ---------------------------------------------------------------------------
// G = W @ W^T  (64x64). One block.
// ---------------------------------------------------------------------------
__global__ __launch_bounds__(256) void make_G(const float* __restrict__ W,
                                              float* __restrict__ G) {
    __shared__ float Ws[64 * 64];
    for (int t = threadIdx.x; t < 64 * 64; t += 256) Ws[t] = W[t];
    __syncthreads();
    for (int t = threadIdx.x; t < 64 * 64; t += 256) {
        int i = t >> 6, j = t & 63;
        float acc = 0.f;
#pragma unroll 8
        for (int k = 0; k < 64; ++k) acc += Ws[i * 64 + k] * Ws[j * 64 + k];
        G[t] = acc;
    }
}

// ---------------------------------------------------------------------------
// extractor: xh = x@We^T + be ; h0 = KTANH*(xh@U^T + bU) ; xU = (xh@U^T+bU)/nf
// ---------------------------------------------------------------------------
__global__ __launch_bounds__(256) void extractor(
        const float* __restrict__ x, const float* __restrict__ nf,
        const float* __restrict__ We, const float* __restrict__ be,
        const float* __restrict__ U,  const float* __restrict__ bU,
        float* __restrict__ xh, float* __restrict__ xU, float* __restrict__ h0) {
    __shared__ float WeT[INC * HH];
    __shared__ float UT[HH * HH];
    __shared__ float beS[HH], bUS[HH];
    __shared__ float xs[4][INC];
    __shared__ float xhs[4][HH];

    for (int t = threadIdx.x; t < INC * HH; t += 256) {
        int j = t >> 7, k = t & 127;
        WeT[k * 64 + j] = We[t];
    }
    for (int t = threadIdx.x; t < HH * HH; t += 256) {
        int j = t >> 6, k = t & 63;
        UT[k * 64 + j] = U[t];
    }
    if (threadIdx.x < 64) { beS[threadIdx.x] = be[threadIdx.x]; bUS[threadIdx.x] = bU[threadIdx.x]; }
    __syncthreads();

    int lane = threadIdx.x & 63;
    int wv   = threadIdx.x >> 6;

    for (int n0 = blockIdx.x * 4; n0 < NN; n0 += gridDim.x * 4) {
        int n = n0 + wv;
        bool valid = n < NN;
        if (valid) {
            xs[wv][lane]      = x[(size_t)n * INC + lane];
            xs[wv][lane + 64] = x[(size_t)n * INC + lane + 64];
        }
        __syncthreads();
        float acc = beS[lane];
        if (valid) {
#pragma unroll 8
            for (int k = 0; k < INC; ++k) acc += xs[wv][k] * WeT[k * 64 + lane];
            xh[n * 64 + lane] = acc;
            xhs[wv][lane] = acc;
        }
        __syncthreads();
        if (valid) {
            float acc2 = bUS[lane];
#pragma unroll 8
            for (int k = 0; k < HH; ++k) acc2 += xhs[wv][k] * UT[k * 64 + lane];
            h0[n * 64 + lane] = KTANH * acc2;
            xU[n * 64 + lane] = acc2 / nf[n];
        }
        __syncthreads();
    }
}

// ---------------------------------------------------------------------------
// fused step v8 (R14): node-centric CSR walk with software-pipelined
// prologues: next-node ev/h loads issued at node start, next-chunk first
// gathers issued at chunk midpoint, next-node first gathers issued before
// the epilogue (G-matvec hides them), depth-2 in-loop gather prefetch.
// ---------------------------------------------------------------------------
__global__ __launch_bounds__(256) void fused_step(
        const int* __restrict__ adj, const int* __restrict__ offs,
        const int* __restrict__ cnt,
        const float* __restrict__ hcur, float* __restrict__ hnxt,
        const float* __restrict__ nf, const float* __restrict__ gamma,
        const float* __restrict__ beta, const float* __restrict__ Gm,
        const float* __restrict__ xU,
        float* __restrict__ y, float* __restrict__ s, int first, int last) {
    __shared__ float Gs[64 * 64];
    for (int t = threadIdx.x; t < 64 * 64; t += 256) Gs[t] = Gm[t];
    __syncthreads();

    const int lane = threadIdx.x & 63, wv = threadIdx.x >> 6;
    const float g = gamma[lane], b = beta[lane];

    v4i_t hsr;
    {
        unsigned long long up = (unsigned long long)(uintptr_t)hcur;
        hsr.x = (int)(unsigned)(up & 0xffffffffull);
        hsr.y = (int)(unsigned)(up >> 32);
        hsr.z = NN * HH * 4;
        hsr.w = 0x00020000;
    }
    const int lane4 = lane << 2;
#define GATH(e) llvm_amdgcn_raw_buffer_load_fp32(hsr, lane4, (e) & 0x00ffff00, 0)
#define RL(v, i) __builtin_amdgcn_readlane((v), (i))

    const int NW = 2048 * 4;
    int n = blockIdx.x * 4 + wv;   // NW < NN so always valid

    // prologue for first node (one-time exposed latency)
    int base = __builtin_amdgcn_readfirstlane(offs[n]);
    int deg  = __builtin_amdgcn_readfirstlane(cnt[n]);
    int evA  = adj[base + lane];
    float hn = hcur[(size_t)n * 64 + lane];
    float a0 = GATH(RL(evA, 0));
    float a1 = GATH(RL(evA, 1));
    float a2 = GATH(RL(evA, 2));
    float a3 = GATH(RL(evA, 3));

    for (;;) {
        const int nfull = deg >> 6;
        const int rem   = deg & 63;
        const int nch   = nfull + (rem ? 1 : 0);
        float accM = 0.f;
        int sigma = 0;

        // ---- issue next-node scalar state + ev + h loads NOW (consumed
        //      ~5000cy later); first gathers issued before the epilogue.
        const int nxt = n + NW;
        const bool more = (nxt < NN);
        int baseN = 0, degN = 0, evN = 0;
        float hnN = 0.f;
        if (more) {
            baseN = __builtin_amdgcn_readfirstlane(offs[nxt]);
            degN  = __builtin_amdgcn_readfirstlane(cnt[nxt]);
            evN   = adj[baseN + lane];
            hnN   = hcur[(size_t)nxt * 64 + lane];
        }

        // ---- next-chunk ev (consumed at this chunk's midpoint for gathers)
        int evB = 0;
        if (nch > 1) evB = adj[base + 64 + lane];

        int   evC = evA;
        float c0 = a0, c1 = a1, c2 = a2, c3 = a3;
        float gB0 = 0.f, gB1 = 0.f, gB2 = 0.f, gB3 = 0.f;

        // ---- full 64-edge chunks, depth-2 gather pipeline
        for (int c = 0; c < nfull; ++c) {
            sigma += 64 - 2 * (int)__builtin_popcountll(__ballot(evC < 0));
            float n0 = GATH(RL(evC, 4));
            float n1 = GATH(RL(evC, 5));
            float n2 = GATH(RL(evC, 6));
            float n3 = GATH(RL(evC, 7));
#pragma unroll
            for (int q = 0; q < 16; ++q) {
                const int j0 = q << 2;
                float w0 = 0.f, w1 = 0.f, w2 = 0.f, w3 = 0.f;
                if (q < 14) {
                    w0 = GATH(RL(evC, j0 + 8));
                    w1 = GATH(RL(evC, j0 + 9));
                    w2 = GATH(RL(evC, j0 + 10));
                    w3 = GATH(RL(evC, j0 + 11));
                }
                if (q == 7 && c + 1 < nch) {
                    // midpoint: next chunk's first-4 gathers (evB arrived)
                    gB0 = GATH(RL(evB, 0));
                    gB1 = GATH(RL(evB, 1));
                    gB2 = GATH(RL(evB, 2));
                    gB3 = GATH(RL(evB, 3));
                }
                accM += quad_contrib<false>(hn, c0, c1, c2, c3, 0, 64);
                c0 = n0; c1 = n1; c2 = n2; c3 = n3;
                n0 = w0; n1 = w1; n2 = w2; n3 = w3;
            }
            if (c + 1 < nch) {
                evC = evB;
                c0 = gB0; c1 = gB1; c2 = gB2; c3 = gB3;
                if (c + 2 < nch) evB = adj[base + ((c + 2) << 6) + lane];
            }
        }

        // ---- remainder chunk (always last), guarded, clamp-free
        if (rem) {
            unsigned long long bal = __ballot(evC < 0);
            unsigned long long msk = (1ull << rem) - 1ull;
            sigma += rem - 2 * (int)__builtin_popcountll(bal & msk);
            const int quads = (rem + 3) >> 2;
            for (int q = 0; q < quads; ++q) {
                const int j0 = q << 2;
                float n0 = GATH(RL(evC, (j0 + 4) & 63));
                float n1 = GATH(RL(evC, (j0 + 5) & 63));
                float n2 = GATH(RL(evC, (j0 + 6) & 63));
                float n3 = GATH(RL(evC, (j0 + 7) & 63));
                accM += quad_contrib<true>(hn, c0, c1, c2, c3, j0, rem);
                c0 = n0; c1 = n1; c2 = n2; c3 = n3;
            }
        }

        // ---- next-node first-4 gathers (evN arrived long ago); the
        //      epilogue below hides their latency.
        float gN0 = 0.f, gN1 = 0.f, gN2 = 0.f, gN3 = 0.f;
        if (more) {
            gN0 = GATH(RL(evN, 0));
            gN1 = GATH(RL(evN, 1));
            gN2 = GATH(RL(evN, 2));
            gN3 = GATH(RL(evN, 3));
        }

        // ---- epilogue
        const float nfn = nf[n];
        const float av  = nfn * __builtin_fmaf(g, accM, b * (float)sigma);

        float p = 0.f;
        const int avi = __float_as_int(av);
#pragma unroll
        for (int k = 0; k < 64; ++k) {
            float ak = __int_as_float(RL(avi, k));
            p = __builtin_fmaf(ak, Gs[k * 64 + lane], p);
        }

        float yprev = 0.f, sprev = 0.f;
        if (!first) {
            yprev = y[n * 64 + lane];
            sprev = s[n * 64 + lane];
        }
        const float yv = -ALPHA * p + (1.0f - ALPHA) * yprev;
        y[n * 64 + lane] = yv;
        s[n * 64 + lane] = (1.0f - ALPHA) * sprev + av;
        if (!last) hnxt[n * 64 + lane] = KTANH * (nfn * (yv + xU[n * 64 + lane]));

        if (!more) break;
        n = nxt; base = baseN; deg = degN;
        evA = evN; a0 = gN0; a1 = gN1; a2 = gN2; a3 = gN3;
        hn = hnN;
    }
#undef GATH
#undef RL
}

// ---------------------------------------------------------------------------
// final: z = -alpha*(s@W) ; zf = nf*z + xh ; out = zf@Wlast^T + blast
// ---------------------------------------------------------------------------
__global__ __launch_bounds__(256) void final_out(
        const float* __restrict__ s, const float* __restrict__ xh,
        const float* __restrict__ nf, const float* __restrict__ W,
        const float* __restrict__ Wlast, const float* __restrict__ blast,
        float* __restrict__ out) {
    __shared__ float Ws[64 * 64];
    __shared__ float WlT[64 * OUTC];
    __shared__ float blS[OUTC];
    __shared__ float ss[4][64];
    __shared__ float zfs[4][64];
    for (int t = threadIdx.x; t < 64 * 64; t += 256) Ws[t] = W[t];
    for (int t = threadIdx.x; t < OUTC * 64; t += 256) {
        int o = t >> 6, j = t & 63;
        WlT[j * OUTC + o] = Wlast[t];
    }
    if (threadIdx.x < OUTC) blS[threadIdx.x] = blast[threadIdx.x];
    __syncthreads();
    int lane = threadIdx.x & 63, wv = threadIdx.x >> 6;
    for (int n0 = blockIdx.x * 4; n0 < NN; n0 += gridDim.x * 4) {
        int n = n0 + wv;
        if (n < NN) ss[wv][lane] = s[n * 64 + lane];
        __syncthreads();
        if (n < NN) {
            float z = 0.f;
#pragma unroll 8
            for (int k = 0; k < 64; ++k) z += ss[wv][k] * Ws[k * 64 + lane];
            z *= -ALPHA;
            zfs[wv][lane] = nf[n] * z + xh[n * 64 + lane];
        }
        __syncthreads();
        if (n < NN && lane < OUTC) {
            float acc = blS[lane];
#pragma unroll 8
            for (int j = 0; j < 64; ++j) acc += zfs[wv][j] * WlT[j * OUTC + lane];
            out[n * OUTC + lane] = acc;
        }
        __syncthreads();
    }
}

// ---------------------------------------------------------------------------
extern "C" void kernel_launch(void* const* d_in, const int* in_sizes, int n_in,
                              void* d_out, int out_size, void* d_ws, size_t ws_size,
                              hipStream_t stream) {
    const float* x     = (const float*)d_in[0];
    const int*   ei    = (const int*)  d_in[1];
    const float* nf    = (const float*)d_in[2];
    const float* We    = (const float*)d_in[3];
    const float* be    = (const float*)d_in[4];
    const float* W     = (const float*)d_in[5];
    const float* U     = (const float*)d_in[6];
    const float* bU    = (const float*)d_in[7];
    const float* gamma = (const float*)d_in[8];
    const float* beta  = (const float*)d_in[9];
    const float* Wlast = (const float*)d_in[10];
    const float* blast = (const float*)d_in[11];
    float* out = (float*)d_out;

    char* ws = (char*)d_ws;
    size_t off = 0;
    const size_t NH = (size_t)NN * HH * sizeof(float);
    int*   adj    = (int*)(ws + off);            off += (size_t)2 * EE * sizeof(int);
    unsigned short* rank16 = (unsigned short*)(ws + off);
                                                 off += (size_t)2 * EE * sizeof(unsigned short);
    int*   offs   = (int*)(ws + off);            off += (size_t)NN * sizeof(int);
    int*   cnt    = (int*)(ws + off);            off += (size_t)NN * sizeof(int);
    int*   bsum   = (int*)(ws + off);            off += 256 * sizeof(int);
    float* xh     = (float*)(ws + off);          off += NH;
    float* xU     = (float*)(ws + off);          off += NH;
    float* h0     = (float*)(ws + off);          off += NH;
    float* h1     = (float*)(ws + off);          off += NH;
    float* y      = (float*)(ws + off);          off += NH;
    float* s      = (float*)(ws + off);          off += NH;
    float* G      = (float*)(ws + off);          off += (size_t)HH * HH * sizeof(float);

    hipMemsetAsync(cnt, 0, (size_t)NN * sizeof(int), stream);
    // y/s zero-init folded into fused_step (first=1)

    // CSR build (once per launch): atomic count (+rank capture), scan,
    // atomic-free fill.
    csr_count<<<(2 * EE + 255) / 256, 256, 0, stream>>>(ei, cnt, rank16);
    scanA<<<NB_SCAN, 256, 0, stream>>>(cnt, offs, bsum);
    scanB<<<1, 256, 0, stream>>>(bsum);
    scanC<<<NB_SCAN, 256, 0, stream>>>(offs, bsum);
    csr_fill<<<(2 * EE + 255) / 256, 256, 0, stream>>>(ei, offs, rank16, adj);

    make_G<<<1, 256, 0, stream>>>(W, G);
    extractor<<<2048, 256, 0, stream>>>(x, nf, We, be, U, bU, xh, xU, h0);

    float* hc = h0;
    float* hn = h1;
    for (int t = 0; t < 4; ++t) {
        fused_step<<<2048, 256, 0, stream>>>(adj, offs, cnt, hc, hn, nf,
                                             gamma, beta, G, xU, y, s,
                                             t == 0, t == 3);
        float* tmp = hc; hc = hn; hn = tmp;
    }
    final_out<<<2048, 256, 0, stream>>>(s, xh, nf, W, Wlast, blast, out);
}

// Round 4
// 1071.977 us; speedup vs baseline: 2.7702x; 1.2373x over previous
//
#include <hip/hip_runtime.h>
#include <hip/hip_bf16.h>

// Problem constants (from reference)
#define NN   50000
#define EE   1600000
#define INC  128
#define HH   64
#define OUTC 40
#define ALPHA 0.8f
#define LN_EPS 1e-5f
#define NB_SCAN 196   // ceil(NN/256)
// h is stored pre-scaled by 2*log2(e) so tanh needs no per-edge multiply:
// tanh(x) = 1 - 2/(1 + 2^(KTANH*x))
#define KTANH 2.8853900817779268f

typedef int v4i_t __attribute__((ext_vector_type(4)));
typedef _Float16 h8 __attribute__((ext_vector_type(8)));
typedef float f32x4 __attribute__((ext_vector_type(4)));

__device__ float llvm_amdgcn_raw_buffer_load_fp32(v4i_t srsrc, int voffset,
                                                  int soffset, int glc_slc)
    __asm("llvm.amdgcn.raw.buffer.load.f32");

__device__ __forceinline__ float rl63(float x) {
    return __int_as_float(__builtin_amdgcn_readlane(__float_as_int(x), 63));
}
#define RLF(X, L) __int_as_float(__builtin_amdgcn_readlane(__float_as_int(X), (L)))

// input already pre-scaled by KTANH: tanh = 1 - 2/(1 + 2^xs)
__device__ __forceinline__ float fast_tanh_pre(float xs) {
    float e = __builtin_amdgcn_exp2f(xs);
    float u = __builtin_amdgcn_rcpf(1.0f + e);
    return __builtin_fmaf(-2.0f, u, 1.0f);
}

struct TileAcc { float a0, a1, a2, a3, sc; };

// ---------------------------------------------------------------------------
// 16-edge tile: d already computed per lane (lane = feature). Write d,d^2 as
// f16 into the wave's LDS tile [16 rows x 64 feats, XOR-swizzled 16B blocks],
// then 4 x mfma_f32_16x16x32_f16 with B = all-ones produce per-edge
// S1 = sum_k d, S2 = sum_k d^2 (B=ones makes the k-permutation of the A
// fragment irrelevant; only row = lane&15 matters). LN scalars run
// lane-parallel (each lane: 4 edges), rsig broadcast via readlane into
// 4 independent accumulator chains.  GUARD zeroes edges >= nrem.
// ---------------------------------------------------------------------------
template <bool GUARD>
__device__ __forceinline__ void tile16(
        TileAcc& A, float hn, int nrem,
        float h0, float h1, float h2, float h3,
        float h4, float h5, float h6, float h7,
        float h8v, float h9, float h10, float h11,
        float h12, float h13, float h14, float h15,
        _Float16* tb, int wt, int wlow, int roff0, int roff1, h8 ones) {
    float d0 = fast_tanh_pre(hn - h0);
    float d1 = fast_tanh_pre(hn - h1);
    float d2 = fast_tanh_pre(hn - h2);
    float d3 = fast_tanh_pre(hn - h3);
    float d4 = fast_tanh_pre(hn - h4);
    float d5 = fast_tanh_pre(hn - h5);
    float d6 = fast_tanh_pre(hn - h6);
    float d7 = fast_tanh_pre(hn - h7);
    float d8 = fast_tanh_pre(hn - h8v);
    float d9 = fast_tanh_pre(hn - h9);
    float d10 = fast_tanh_pre(hn - h10);
    float d11 = fast_tanh_pre(hn - h11);
    float d12 = fast_tanh_pre(hn - h12);
    float d13 = fast_tanh_pre(hn - h13);
    float d14 = fast_tanh_pre(hn - h14);
    float d15 = fast_tanh_pre(hn - h15);
    if (GUARD) {
        // wave-uniform conditions; invalid edges contribute exactly 0
        // (d=0 -> S1=S2=0 -> mu=0 -> rsig*mu=0, and fma adds rsig*0)
        if (!(0 < nrem))  d0 = 0.f;
        if (!(1 < nrem))  d1 = 0.f;
        if (!(2 < nrem))  d2 = 0.f;
        if (!(3 < nrem))  d3 = 0.f;
        if (!(4 < nrem))  d4 = 0.f;
        if (!(5 < nrem))  d5 = 0.f;
        if (!(6 < nrem))  d6 = 0.f;
        if (!(7 < nrem))  d7 = 0.f;
        if (!(8 < nrem))  d8 = 0.f;
        if (!(9 < nrem))  d9 = 0.f;
        if (!(10 < nrem)) d10 = 0.f;
        if (!(11 < nrem)) d11 = 0.f;
        if (!(12 < nrem)) d12 = 0.f;
        if (!(13 < nrem)) d13 = 0.f;
        if (!(14 < nrem)) d14 = 0.f;
        if (!(15 < nrem)) d15 = 0.f;
    }
    // writes: row e (128B logical) with 16B-block XOR swizzle by (e&7)
#define WRT(E, D)                                                             \
    {                                                                         \
        int ix = ((wt ^ ((E) & 7)) << 3) + wlow + ((E) << 6);                 \
        tb[ix] = (_Float16)(D);                                               \
        tb[ix + 1024] = (_Float16)((D) * (D));                                \
    }
    WRT(0, d0)   WRT(1, d1)   WRT(2, d2)   WRT(3, d3)
    WRT(4, d4)   WRT(5, d5)   WRT(6, d6)   WRT(7, d7)
    WRT(8, d8)   WRT(9, d9)   WRT(10, d10) WRT(11, d11)
    WRT(12, d12) WRT(13, d13) WRT(14, d14) WRT(15, d15)
#undef WRT
    h8 a0 = *(const h8*)(tb + roff0);
    h8 a1 = *(const h8*)(tb + roff1);
    h8 q0 = *(const h8*)(tb + 1024 + roff0);
    h8 q1 = *(const h8*)(tb + 1024 + roff1);
    f32x4 s1 = {0.f, 0.f, 0.f, 0.f}, s2 = {0.f, 0.f, 0.f, 0.f};
    s1 = __builtin_amdgcn_mfma_f32_16x16x32_f16(a0, ones, s1, 0, 0, 0);
    s1 = __builtin_amdgcn_mfma_f32_16x16x32_f16(a1, ones, s1, 0, 0, 0);
    s2 = __builtin_amdgcn_mfma_f32_16x16x32_f16(q0, ones, s2, 0, 0, 0);
    s2 = __builtin_amdgcn_mfma_f32_16x16x32_f16(q1, ones, s2, 0, 0, 0);
    // LN stats: lane holds rows 4*(lane>>4)+r  (edge = row)
    float mu0 = s1[0] * 0.015625f;
    float mu1 = s1[1] * 0.015625f;
    float mu2 = s1[2] * 0.015625f;
    float mu3 = s1[3] * 0.015625f;
    float v0 = __builtin_fmaf(s2[0], 0.015625f, __builtin_fmaf(-mu0, mu0, LN_EPS));
    float v1 = __builtin_fmaf(s2[1], 0.015625f, __builtin_fmaf(-mu1, mu1, LN_EPS));
    float v2 = __builtin_fmaf(s2[2], 0.015625f, __builtin_fmaf(-mu2, mu2, LN_EPS));
    float v3 = __builtin_fmaf(s2[3], 0.015625f, __builtin_fmaf(-mu3, mu3, LN_EPS));
    float rs0 = __frsqrt_rn(v0);
    float rs1 = __frsqrt_rn(v1);
    float rs2 = __frsqrt_rn(v2);
    float rs3 = __frsqrt_rn(v3);
    // per-lane partial of sum_e rsig_e*mu_e over this lane-group's 4 edges;
    // groups combined by 2-stage row_bcast (adds one representative per row)
    float cs = __builtin_fmaf(rs0, mu0,
               __builtin_fmaf(rs1, mu1,
               __builtin_fmaf(rs2, mu2, rs3 * mu3)));
    asm volatile(
        "s_nop 1\n\t"
        "v_add_f32_dpp %0, %0, %0 row_bcast:15 row_mask:0xa bank_mask:0xf bound_ctrl:0\n\t"
        "s_nop 1\n\t"
        "v_add_f32_dpp %0, %0, %0 row_bcast:31 row_mask:0xc bank_mask:0xf bound_ctrl:0"
        : "+v"(cs));
    A.sc += rl63(cs);
    // accM folds: edge e -> (reg e&3, lane 16*(e>>2)); 4 independent chains
    A.a0 = __builtin_fmaf(RLF(rs0, 0), d0, A.a0);
    A.a1 = __builtin_fmaf(RLF(rs1, 0), d1, A.a1);
    A.a2 = __builtin_fmaf(RLF(rs2, 0), d2, A.a2);
    A.a3 = __builtin_fmaf(RLF(rs3, 0), d3, A.a3);
    A.a0 = __builtin_fmaf(RLF(rs0, 16), d4, A.a0);
    A.a1 = __builtin_fmaf(RLF(rs1, 16), d5, A.a1);
    A.a2 = __builtin_fmaf(RLF(rs2, 16), d6, A.a2);
    A.a3 = __builtin_fmaf(RLF(rs3, 16), d7, A.a3);
    A.a0 = __builtin_fmaf(RLF(rs0, 32), d8, A.a0);
    A.a1 = __builtin_fmaf(RLF(rs1, 32), d9, A.a1);
    A.a2 = __builtin_fmaf(RLF(rs2, 32), d10, A.a2);
    A.a3 = __builtin_fmaf(RLF(rs3, 32), d11, A.a3);
    A.a0 = __builtin_fmaf(RLF(rs0, 48), d12, A.a0);
    A.a1 = __builtin_fmaf(RLF(rs1, 48), d13, A.a1);
    A.a2 = __builtin_fmaf(RLF(rs2, 48), d14, A.a2);
    A.a3 = __builtin_fmaf(RLF(rs3, 48), d15, A.a3);
}

// ---------------------------------------------------------------------------
// CSR build, atomic-light: count returns per-node rank; fill is
// atomic-free scattered stores (L2-absorbed).
// adj entry encoding: (other<<8) | (role<<31)
// ---------------------------------------------------------------------------
__global__ __launch_bounds__(256) void csr_count(const int* __restrict__ ei,
                                                 int* __restrict__ cnt,
                                                 unsigned short* __restrict__ rank16) {
    int i = blockIdx.x * 256 + threadIdx.x;
    if (i >= 2 * EE) return;
    int r = atomicAdd(&cnt[ei[i]], 1);
    rank16[i] = (unsigned short)r;
}

__global__ __launch_bounds__(256) void scanA(const int* __restrict__ cnt,
                                             int* __restrict__ offs,
                                             int* __restrict__ bsum) {
    __shared__ int tmp[256];
    int i = blockIdx.x * 256 + threadIdx.x;
    int v = (i < NN) ? cnt[i] : 0;
    tmp[threadIdx.x] = v;
    __syncthreads();
    int acc = v;
    for (int d = 1; d < 256; d <<= 1) {
        int t = (threadIdx.x >= d) ? tmp[threadIdx.x - d] : 0;
        __syncthreads();
        acc += t;
        tmp[threadIdx.x] = acc;
        __syncthreads();
    }
    if (i < NN) offs[i] = acc - v;
    if (threadIdx.x == 255) bsum[blockIdx.x] = acc;
}

__global__ __launch_bounds__(256) void scanB(int* __restrict__ bsum) {
    __shared__ int tmp[256];
    int v = (threadIdx.x < NB_SCAN) ? bsum[threadIdx.x] : 0;
    tmp[threadIdx.x] = v;
    __syncthreads();
    int acc = v;
    for (int d = 1; d < 256; d <<= 1) {
        int t = (threadIdx.x >= d) ? tmp[threadIdx.x - d] : 0;
        __syncthreads();
        acc += t;
        tmp[threadIdx.x] = acc;
        __syncthreads();
    }
    if (threadIdx.x < NB_SCAN) bsum[threadIdx.x] = acc - v;
}

__global__ __launch_bounds__(256) void scanC(int* __restrict__ offs,
                                             const int* __restrict__ bsum) {
    int i = blockIdx.x * 256 + threadIdx.x;
    if (i < NN) offs[i] += bsum[blockIdx.x];
}

__global__ __launch_bounds__(256) void csr_fill(const int* __restrict__ ei,
                                                const int* __restrict__ offs,
                                                const unsigned short* __restrict__ rank16,
                                                int* __restrict__ adj) {
    int i = blockIdx.x * 256 + threadIdx.x;
    if (i >= 2 * EE) return;
    int node  = ei[i];
    int role  = (i >= EE) ? 1 : 0;
    int other = role ? ei[i - EE] : ei[i + EE];
    adj[offs[node] + (int)rank16[i]] =
        (int)(((unsigned)other << 8) | ((unsigned)role << 31));
}

// ---------------------------------------------------------------------------
// G = W @ W^T  (64x64). One block.
// ---------------------------------------------------------------------------
__global__ __launch_bounds__(256) void make_G(const float* __restrict__ W,
                                              float* __restrict__ G) {
    __shared__ float Ws[64 * 64];
    for (int t = threadIdx.x; t < 64 * 64; t += 256) Ws[t] = W[t];
    __syncthreads();
    for (int t = threadIdx.x; t < 64 * 64; t += 256) {
        int i = t >> 6, j = t & 63;
        float acc = 0.f;
#pragma unroll 8
        for (int k = 0; k < 64; ++k) acc += Ws[i * 64 + k] * Ws[j * 64 + k];
        G[t] = acc;
    }
}

// ---------------------------------------------------------------------------
// extractor: xh = x@We^T + be ; h0 = KTANH*(xh@U^T + bU) ; xU = (xh@U^T+bU)/nf
// ---------------------------------------------------------------------------
__global__ __launch_bounds__(256) void extractor(
        const float* __restrict__ x, const float* __restrict__ nf,
        const float* __restrict__ We, const float* __restrict__ be,
        const float* __restrict__ U,  const float* __restrict__ bU,
        float* __restrict__ xh, float* __restrict__ xU, float* __restrict__ h0) {
    __shared__ float WeT[INC * HH];
    __shared__ float UT[HH * HH];
    __shared__ float beS[HH], bUS[HH];
    __shared__ float xs[4][INC];
    __shared__ float xhs[4][HH];

    for (int t = threadIdx.x; t < INC * HH; t += 256) {
        int j = t >> 7, k = t & 127;
        WeT[k * 64 + j] = We[t];
    }
    for (int t = threadIdx.x; t < HH * HH; t += 256) {
        int j = t >> 6, k = t & 63;
        UT[k * 64 + j] = U[t];
    }
    if (threadIdx.x < 64) { beS[threadIdx.x] = be[threadIdx.x]; bUS[threadIdx.x] = bU[threadIdx.x]; }
    __syncthreads();

    int lane = threadIdx.x & 63;
    int wv   = threadIdx.x >> 6;

    for (int n0 = blockIdx.x * 4; n0 < NN; n0 += gridDim.x * 4) {
        int n = n0 + wv;
        bool valid = n < NN;
        if (valid) {
            xs[wv][lane]      = x[(size_t)n * INC + lane];
            xs[wv][lane + 64] = x[(size_t)n * INC + lane + 64];
        }
        __syncthreads();
        float acc = beS[lane];
        if (valid) {
#pragma unroll 8
            for (int k = 0; k < INC; ++k) acc += xs[wv][k] * WeT[k * 64 + lane];
            xh[n * 64 + lane] = acc;
            xhs[wv][lane] = acc;
        }
        __syncthreads();
        if (valid) {
            float acc2 = bUS[lane];
#pragma unroll 8
            for (int k = 0; k < HH; ++k) acc2 += xhs[wv][k] * UT[k * 64 + lane];
            h0[n * 64 + lane] = KTANH * acc2;
            xU[n * 64 + lane] = acc2 / nf[n];
        }
        __syncthreads();
    }
}

// ---------------------------------------------------------------------------
// fused step v10 (R15): MFMA-assisted LN stats. 16-edge tiles; batched
// gathers one tile ahead; DPP reduce + redundant per-lane LN replaced by
// f16 LDS tile + 4x mfma(A, ones) + lane-parallel LN + readlane folds.
// ---------------------------------------------------------------------------
#define HV(P) P##0, P##1, P##2, P##3, P##4, P##5, P##6, P##7,                 \
              P##8, P##9, P##10, P##11, P##12, P##13, P##14, P##15

#define G16(P, EV, J)                                                          \
    do {                                                                       \
        P##0  = GATH(RL(EV, (J) + 0));  P##1  = GATH(RL(EV, (J) + 1));         \
        P##2  = GATH(RL(EV, (J) + 2));  P##3  = GATH(RL(EV, (J) + 3));         \
        P##4  = GATH(RL(EV, (J) + 4));  P##5  = GATH(RL(EV, (J) + 5));         \
        P##6  = GATH(RL(EV, (J) + 6));  P##7  = GATH(RL(EV, (J) + 7));         \
        P##8  = GATH(RL(EV, (J) + 8));  P##9  = GATH(RL(EV, (J) + 9));         \
        P##10 = GATH(RL(EV, (J) + 10)); P##11 = GATH(RL(EV, (J) + 11));        \
        P##12 = GATH(RL(EV, (J) + 12)); P##13 = GATH(RL(EV, (J) + 13));        \
        P##14 = GATH(RL(EV, (J) + 14)); P##15 = GATH(RL(EV, (J) + 15));        \
    } while (0)

#define NEXTPREF(P)                                                            \
    do {                                                                       \
        if (morechunk)      { G16(P, evB, 0); }                                \
        else if (morenode)  { G16(P, evN, 0); }                                \
    } while (0)

__global__ __launch_bounds__(256) void fused_step(
        const int* __restrict__ adj, const int* __restrict__ offs,
        const int* __restrict__ cnt,
        const float* __restrict__ hcur, float* __restrict__ hnxt,
        const float* __restrict__ nf, const float* __restrict__ gamma,
        const float* __restrict__ beta, const float* __restrict__ Gm,
        const float* __restrict__ xU,
        float* __restrict__ y, float* __restrict__ s, int first, int last) {
    __shared__ float Gs[64 * 64];
    __shared__ __align__(16) _Float16 dt[4][2048];
    for (int t = threadIdx.x; t < 64 * 64; t += 256) Gs[t] = Gm[t];
    __syncthreads();

    const int lane = threadIdx.x & 63, wv = threadIdx.x >> 6;
    const float g = gamma[lane], b = beta[lane];

    v4i_t hsr;
    {
        unsigned long long up = (unsigned long long)(uintptr_t)hcur;
        hsr.x = (int)(unsigned)(up & 0xffffffffull);
        hsr.y = (int)(unsigned)(up >> 32);
        hsr.z = NN * HH * 4;
        hsr.w = 0x00020000;
    }
    const int lane4 = lane << 2;
#define GATH(e) llvm_amdgcn_raw_buffer_load_fp32(hsr, lane4, (e) & 0x00ffff00, 0)
#define RL(v, i) __builtin_amdgcn_readlane((v), (i))

    _Float16* tb = &dt[wv][0];
    const int wt   = lane >> 3;        // write: 16B block index of this feat
    const int wlow = lane & 7;         // write: elem within block
    const int re = lane & 15, rg = lane >> 4, rc = lane & 7;
    const int roff0 = re * 64 + ((rg) ^ rc) * 8;       // frag read, MFMA 0
    const int roff1 = re * 64 + ((4 + rg) ^ rc) * 8;   // frag read, MFMA 1
    const h8 ones = {(_Float16)1.f, (_Float16)1.f, (_Float16)1.f, (_Float16)1.f,
                     (_Float16)1.f, (_Float16)1.f, (_Float16)1.f, (_Float16)1.f};

    const int NW = 2048 * 4;
    int n = blockIdx.x * 4 + wv;       // NW < NN so always valid
    int base = __builtin_amdgcn_readfirstlane(offs[n]);
    int deg  = __builtin_amdgcn_readfirstlane(cnt[n]);
    int ev   = adj[base + lane];
    float hn = hcur[(size_t)n * 64 + lane];
    float hA0, hA1, hA2, hA3, hA4, hA5, hA6, hA7;
    float hA8, hA9, hA10, hA11, hA12, hA13, hA14, hA15;
    float hB0, hB1, hB2, hB3, hB4, hB5, hB6, hB7;
    float hB8, hB9, hB10, hB11, hB12, hB13, hB14, hB15;
    G16(hA, ev, 0);

    for (;;) {
        const int nxt = n + NW;
        const bool morenode = nxt < NN;
        int baseN = 0, degN = 0, evN = 0;
        float hnN = 0.f;
        if (morenode) {
            baseN = __builtin_amdgcn_readfirstlane(offs[nxt]);
            degN  = __builtin_amdgcn_readfirstlane(cnt[nxt]);
            evN   = adj[baseN + lane];
            hnN   = hcur[(size_t)nxt * 64 + lane];
        }
        TileAcc A = {0.f, 0.f, 0.f, 0.f, 0.f};
        int sigma = 0;

        if (deg > 0) {
            int cbase = 0;
            for (;;) {
                int nE = deg - cbase;
                if (nE > 64) nE = 64;
                const bool morechunk = (cbase + 64 < deg);
                int evB = 0;
                if (morechunk) evB = adj[base + cbase + 64 + lane];
                unsigned long long bal = __ballot(ev < 0);
                unsigned long long msk =
                    (nE >= 64) ? ~0ull : ((1ull << nE) - 1ull);
                sigma += nE - 2 * (int)__builtin_popcountll(bal & msk);

                if (nE == 64) {
                    G16(hB, ev, 16);
                    tile16<false>(A, hn, 0, HV(hA), tb, wt, wlow, roff0, roff1, ones);
                    G16(hA, ev, 32);
                    tile16<false>(A, hn, 0, HV(hB), tb, wt, wlow, roff0, roff1, ones);
                    G16(hB, ev, 48);
                    tile16<false>(A, hn, 0, HV(hA), tb, wt, wlow, roff0, roff1, ones);
                    NEXTPREF(hA);
                    tile16<false>(A, hn, 0, HV(hB), tb, wt, wlow, roff0, roff1, ones);
                } else {
                    const int nt = (nE + 15) >> 4;
                    if (nt > 1) { G16(hB, ev, 16); } else { NEXTPREF(hB); }
                    tile16<true>(A, hn, nE, HV(hA), tb, wt, wlow, roff0, roff1, ones);
                    if (nt > 1) {
                        if (nt > 2) { G16(hA, ev, 32); } else { NEXTPREF(hA); }
                        tile16<true>(A, hn, nE - 16, HV(hB), tb, wt, wlow, roff0, roff1, ones);
                        if (nt > 2) {
                            if (nt > 3) { G16(hB, ev, 48); } else { NEXTPREF(hB); }
                            tile16<true>(A, hn, nE - 32, HV(hA), tb, wt, wlow, roff0, roff1, ones);
                            if (nt > 3) {
                                NEXTPREF(hA);
                                tile16<true>(A, hn, nE - 48, HV(hB), tb, wt, wlow, roff0, roff1, ones);
                            }
                        }
                    }
                    if (nt & 1) {
                        hA0 = hB0;  hA1 = hB1;  hA2 = hB2;  hA3 = hB3;
                        hA4 = hB4;  hA5 = hB5;  hA6 = hB6;  hA7 = hB7;
                        hA8 = hB8;  hA9 = hB9;  hA10 = hB10; hA11 = hB11;
                        hA12 = hB12; hA13 = hB13; hA14 = hB14; hA15 = hB15;
                    }
                }
                if (!morechunk) break;
                ev = evB;
                cbase += 64;
            }
        } else {
            if (morenode) { G16(hA, evN, 0); }
        }

        // ---- epilogue
        const float accM = ((A.a0 + A.a1) + (A.a2 + A.a3)) - A.sc;
        const float nfn = nf[n];
        const float av  = nfn * __builtin_fmaf(g, accM, b * (float)sigma);

        float p = 0.f;
        const int avi = __float_as_int(av);
#pragma unroll
        for (int k = 0; k < 64; ++k) {
            float ak = __int_as_float(RL(avi, k));
            p = __builtin_fmaf(ak, Gs[k * 64 + lane], p);
        }

        float yprev = 0.f, sprev = 0.f;
        if (!first) {
            yprev = y[n * 64 + lane];
            sprev = s[n * 64 + lane];
        }
        const float yv = -ALPHA * p + (1.0f - ALPHA) * yprev;
        y[n * 64 + lane] = yv;
        s[n * 64 + lane] = (1.0f - ALPHA) * sprev + av;
        if (!last) hnxt[n * 64 + lane] = KTANH * (nfn * (yv + xU[n * 64 + lane]));

        if (!morenode) break;
        n = nxt; base = baseN; deg = degN;
        ev = evN; hn = hnN;
    }
#undef GATH
#undef RL
}

// ---------------------------------------------------------------------------
// final: z = -alpha*(s@W) ; zf = nf*z + xh ; out = zf@Wlast^T + blast
// ---------------------------------------------------------------------------
__global__ __launch_bounds__(256) void final_out(
        const float* __restrict__ s, const float* __restrict__ xh,
        const float* __restrict__ nf, const float* __restrict__ W,
        const float* __restrict__ Wlast, const float* __restrict__ blast,
        float* __restrict__ out) {
    __shared__ float Ws[64 * 64];
    __shared__ float WlT[64 * OUTC];
    __shared__ float blS[OUTC];
    __shared__ float ss[4][64];
    __shared__ float zfs[4][64];
    for (int t = threadIdx.x; t < 64 * 64; t += 256) Ws[t] = W[t];
    for (int t = threadIdx.x; t < OUTC * 64; t += 256) {
        int o = t >> 6, j = t & 63;
        WlT[j * OUTC + o] = Wlast[t];
    }
    if (threadIdx.x < OUTC) blS[threadIdx.x] = blast[threadIdx.x];
    __syncthreads();
    int lane = threadIdx.x & 63, wv = threadIdx.x >> 6;
    for (int n0 = blockIdx.x * 4; n0 < NN; n0 += gridDim.x * 4) {
        int n = n0 + wv;
        if (n < NN) ss[wv][lane] = s[n * 64 + lane];
        __syncthreads();
        if (n < NN) {
            float z = 0.f;
#pragma unroll 8
            for (int k = 0; k < 64; ++k) z += ss[wv][k] * Ws[k * 64 + lane];
            z *= -ALPHA;
            zfs[wv][lane] = nf[n] * z + xh[n * 64 + lane];
        }
        __syncthreads();
        if (n < NN && lane < OUTC) {
            float acc = blS[lane];
#pragma unroll 8
            for (int j = 0; j < 64; ++j) acc += zfs[wv][j] * WlT[j * OUTC + lane];
            out[n * OUTC + lane] = acc;
        }
        __syncthreads();
    }
}

// ---------------------------------------------------------------------------
extern "C" void kernel_launch(void* const* d_in, const int* in_sizes, int n_in,
                              void* d_out, int out_size, void* d_ws, size_t ws_size,
                              hipStream_t stream) {
    const float* x     = (const float*)d_in[0];
    const int*   ei    = (const int*)  d_in[1];
    const float* nf    = (const float*)d_in[2];
    const float* We    = (const float*)d_in[3];
    const float* be    = (const float*)d_in[4];
    const float* W     = (const float*)d_in[5];
    const float* U     = (const float*)d_in[6];
    const float* bU    = (const float*)d_in[7];
    const float* gamma = (const float*)d_in[8];
    const float* beta  = (const float*)d_in[9];
    const float* Wlast = (const float*)d_in[10];
    const float* blast = (const float*)d_in[11];
    float* out = (float*)d_out;

    char* ws = (char*)d_ws;
    size_t off = 0;
    const size_t NH = (size_t)NN * HH * sizeof(float);
    int*   adj    = (int*)(ws + off);            off += (size_t)2 * EE * sizeof(int);
    unsigned short* rank16 = (unsigned short*)(ws + off);
                                                 off += (size_t)2 * EE * sizeof(unsigned short);
    int*   offs   = (int*)(ws + off);            off += (size_t)NN * sizeof(int);
    int*   cnt    = (int*)(ws + off);            off += (size_t)NN * sizeof(int);
    int*   bsum   = (int*)(ws + off);            off += 256 * sizeof(int);
    float* xh     = (float*)(ws + off);          off += NH;
    float* xU     = (float*)(ws + off);          off += NH;
    float* h0     = (float*)(ws + off);          off += NH;
    float* h1     = (float*)(ws + off);          off += NH;
    float* y      = (float*)(ws + off);          off += NH;
    float* s      = (float*)(ws + off);          off += NH;
    float* G      = (float*)(ws + off);          off += (size_t)HH * HH * sizeof(float);

    hipMemsetAsync(cnt, 0, (size_t)NN * sizeof(int), stream);
    // y/s zero-init folded into fused_step (first=1)

    csr_count<<<(2 * EE + 255) / 256, 256, 0, stream>>>(ei, cnt, rank16);
    scanA<<<NB_SCAN, 256, 0, stream>>>(cnt, offs, bsum);
    scanB<<<1, 256, 0, stream>>>(bsum);
    scanC<<<NB_SCAN, 256, 0, stream>>>(offs, bsum);
    csr_fill<<<(2 * EE + 255) / 256, 256, 0, stream>>>(ei, offs, rank16, adj);

    make_G<<<1, 256, 0, stream>>>(W, G);
    extractor<<<2048, 256, 0, stream>>>(x, nf, We, be, U, bU, xh, xU, h0);

    float* hc = h0;
    float* hn = h1;
    for (int t = 0; t < 4; ++t) {
        fused_step<<<2048, 256, 0, stream>>>(adj, offs, cnt, hc, hn, nf,
                                             gamma, beta, G, xU, y, s,
                                             t == 0, t == 3);
        float* tmp = hc; hc = hn; hn = tmp;
    }
    final_out<<<2048, 256, 0, stream>>>(s, xh, nf, W, Wlast, blast, out);
}

// Round 7
// 991.789 us; speedup vs baseline: 2.9942x; 1.0809x over previous
//
#include <hip/hip_runtime.h>
#include <hip/hip_bf16.h>

// Problem constants (from reference)
#define NN   50000
#define EE   1600000
#define INC  128
#define HH   64
#define OUTC 40
#define ALPHA 0.8f
#define LN_EPS 1e-5f
#define NB_SCAN 196   // ceil(NN/256)
// h is stored pre-scaled by 2*log2(e) so tanh needs no per-edge multiply:
// tanh(x) = 1 - 2/(1 + 2^(KTANH*x))
#define KTANH 2.8853900817779268f

typedef int v4i_t __attribute__((ext_vector_type(4)));
typedef _Float16 h8 __attribute__((ext_vector_type(8)));
typedef __fp16 hv2 __attribute__((ext_vector_type(2)));   // cvt_pkrtz's type
typedef float f32x4 __attribute__((ext_vector_type(4)));
typedef int i32x2 __attribute__((ext_vector_type(2)));
typedef int i32x4 __attribute__((ext_vector_type(4)));

__device__ float llvm_amdgcn_raw_buffer_load_fp32(v4i_t srsrc, int voffset,
                                                  int soffset, int glc_slc)
    __asm("llvm.amdgcn.raw.buffer.load.f32");

__device__ __forceinline__ float rl63(float x) {
    return __int_as_float(__builtin_amdgcn_readlane(__float_as_int(x), 63));
}
#define RLF(X, L) __int_as_float(__builtin_amdgcn_readlane(__float_as_int(X), (L)))

// input already pre-scaled by KTANH: tanh = 1 - 2/(1 + 2^xs)
__device__ __forceinline__ float fast_tanh_pre(float xs) {
    float e = __builtin_amdgcn_exp2f(xs);
    float u = __builtin_amdgcn_rcpf(1.0f + e);
    return __builtin_fmaf(-2.0f, u, 1.0f);
}

__device__ __forceinline__ h8 mk8(i32x2 a, i32x2 b) {
    i32x4 t = {a.x, a.y, b.x, b.y};
    return __builtin_bit_cast(h8, t);
}

struct TileAcc { float a0, a1, a2, a3, sc; };

// ---------------------------------------------------------------------------
// 16-edge tile v2 (R16/R18): LDS tile is [64 feat][16 edge] f16 (d @byte 0,
// d^2 @byte 2048). Lane (=feature) packs its 16 d's with v_cvt_pkrtz +
// v_pk_mul_f16 and stores 4x ds_write_b128 (zero address math). A-fragments
// read back with ds_read_b64_tr_b16. TR semantics (guide m156): per 16-lane
// group, lane i loads 8B at its OWN addr; group must read a contiguous
// 4x16-f16 row-major tile with addr = base_g + i*8; HW delivers column i
// (4 rows) to lane i. base_g = tile + (l>>4)*256 covers feature-block 2g;
// offset:128 -> +4 feats; offset:1024/1152 -> feats 32..63; +2048 -> d^2.
// (R6 bug was i*2 instead of i*8.) With B=ones the MFMA row-sum only
// depends on row (=edge = l&15) attribution, which this layout satisfies.
// rsig folds lane-parallel; sum_e rsig_e*mu_e partial stays per-lane
// (row-uniform) and is combined once per node in the epilogue.
// ---------------------------------------------------------------------------
#define TRRD(D, OFF)                                                           \
    asm volatile("ds_read_b64_tr_b16 %0, %1 offset:" OFF                       \
                 : "=v"(D) : "v"(trv))

template <bool GUARD>
__device__ __forceinline__ void tile16(
        TileAcc& A, float hn, int nrem,
        float h0, float h1, float h2, float h3,
        float h4, float h5, float h6, float h7,
        float h8v, float h9, float h10, float h11,
        float h12, float h13, float h14, float h15,
        char* wp, int trv, h8 ones) {
    float d0 = fast_tanh_pre(hn - h0);
    float d1 = fast_tanh_pre(hn - h1);
    float d2 = fast_tanh_pre(hn - h2);
    float d3 = fast_tanh_pre(hn - h3);
    float d4 = fast_tanh_pre(hn - h4);
    float d5 = fast_tanh_pre(hn - h5);
    float d6 = fast_tanh_pre(hn - h6);
    float d7 = fast_tanh_pre(hn - h7);
    float d8 = fast_tanh_pre(hn - h8v);
    float d9 = fast_tanh_pre(hn - h9);
    float d10 = fast_tanh_pre(hn - h10);
    float d11 = fast_tanh_pre(hn - h11);
    float d12 = fast_tanh_pre(hn - h12);
    float d13 = fast_tanh_pre(hn - h13);
    float d14 = fast_tanh_pre(hn - h14);
    float d15 = fast_tanh_pre(hn - h15);
    if (GUARD) {
        // invalid edges contribute exactly 0 (d=0 -> S1=S2=0 -> mu=0)
        if (!(0 < nrem))  d0 = 0.f;
        if (!(1 < nrem))  d1 = 0.f;
        if (!(2 < nrem))  d2 = 0.f;
        if (!(3 < nrem))  d3 = 0.f;
        if (!(4 < nrem))  d4 = 0.f;
        if (!(5 < nrem))  d5 = 0.f;
        if (!(6 < nrem))  d6 = 0.f;
        if (!(7 < nrem))  d7 = 0.f;
        if (!(8 < nrem))  d8 = 0.f;
        if (!(9 < nrem))  d9 = 0.f;
        if (!(10 < nrem)) d10 = 0.f;
        if (!(11 < nrem)) d11 = 0.f;
        if (!(12 < nrem)) d12 = 0.f;
        if (!(13 < nrem)) d13 = 0.f;
        if (!(14 < nrem)) d14 = 0.f;
        if (!(15 < nrem)) d15 = 0.f;
    }
    hv2 p0 = __builtin_amdgcn_cvt_pkrtz(d0, d1);
    hv2 p1 = __builtin_amdgcn_cvt_pkrtz(d2, d3);
    hv2 p2 = __builtin_amdgcn_cvt_pkrtz(d4, d5);
    hv2 p3 = __builtin_amdgcn_cvt_pkrtz(d6, d7);
    hv2 p4 = __builtin_amdgcn_cvt_pkrtz(d8, d9);
    hv2 p5 = __builtin_amdgcn_cvt_pkrtz(d10, d11);
    hv2 p6 = __builtin_amdgcn_cvt_pkrtz(d12, d13);
    hv2 p7 = __builtin_amdgcn_cvt_pkrtz(d14, d15);
    hv2 q0 = p0 * p0, q1 = p1 * p1, q2 = p2 * p2, q3 = p3 * p3;
    hv2 q4 = p4 * p4, q5 = p5 * p5, q6 = p6 * p6, q7 = p7 * p7;
#define BC(X) __builtin_bit_cast(int, X)
    i32x4 wA = {BC(p0), BC(p1), BC(p2), BC(p3)};
    i32x4 wB = {BC(p4), BC(p5), BC(p6), BC(p7)};
    i32x4 wC = {BC(q0), BC(q1), BC(q2), BC(q3)};
    i32x4 wD = {BC(q4), BC(q5), BC(q6), BC(q7)};
#undef BC
    *(i32x4*)(wp)        = wA;
    *(i32x4*)(wp + 16)   = wB;
    *(i32x4*)(wp + 2048) = wC;
    *(i32x4*)(wp + 2064) = wD;
    asm volatile("" ::: "memory");   // keep stores before tr reads (DS is
                                     // in-order per wave at HW level)
    i32x2 r0, r1, r2, r3, r4, r5, r6, r7;
    TRRD(r0, "0");    TRRD(r1, "128");
    TRRD(r2, "1024"); TRRD(r3, "1152");
    TRRD(r4, "2048"); TRRD(r5, "2176");
    TRRD(r6, "3072"); TRRD(r7, "3200");
    asm volatile("s_waitcnt lgkmcnt(0)" ::: "memory");
    __builtin_amdgcn_sched_barrier(0);   // rule 18: no hoisting past the wait
    h8 a0 = mk8(r0, r1), a1 = mk8(r2, r3);
    h8 b0 = mk8(r4, r5), b1 = mk8(r6, r7);
    f32x4 s1 = {0.f, 0.f, 0.f, 0.f}, s2 = {0.f, 0.f, 0.f, 0.f};
    s1 = __builtin_amdgcn_mfma_f32_16x16x32_f16(a0, ones, s1, 0, 0, 0);
    s1 = __builtin_amdgcn_mfma_f32_16x16x32_f16(a1, ones, s1, 0, 0, 0);
    s2 = __builtin_amdgcn_mfma_f32_16x16x32_f16(b0, ones, s2, 0, 0, 0);
    s2 = __builtin_amdgcn_mfma_f32_16x16x32_f16(b1, ones, s2, 0, 0, 0);
    // LN stats: lane holds rows (edges) 4*(lane>>4)+r, all 16 cols equal
    float mu0 = s1[0] * 0.015625f;
    float mu1 = s1[1] * 0.015625f;
    float mu2 = s1[2] * 0.015625f;
    float mu3 = s1[3] * 0.015625f;
    float v0 = __builtin_fmaf(s2[0], 0.015625f, __builtin_fmaf(-mu0, mu0, LN_EPS));
    float v1 = __builtin_fmaf(s2[1], 0.015625f, __builtin_fmaf(-mu1, mu1, LN_EPS));
    float v2 = __builtin_fmaf(s2[2], 0.015625f, __builtin_fmaf(-mu2, mu2, LN_EPS));
    float v3 = __builtin_fmaf(s2[3], 0.015625f, __builtin_fmaf(-mu3, mu3, LN_EPS));
    float rs0 = __frsqrt_rn(v0);
    float rs1 = __frsqrt_rn(v1);
    float rs2 = __frsqrt_rn(v2);
    float rs3 = __frsqrt_rn(v3);
    // per-lane partial of sum_e rsig_e*mu_e (row-uniform); combined per node
    A.sc += __builtin_fmaf(rs0, mu0,
            __builtin_fmaf(rs1, mu1,
            __builtin_fmaf(rs2, mu2, rs3 * mu3)));
    // accM folds: edge e -> (reg e&3, lane 16*(e>>2)); 4 independent chains
    A.a0 = __builtin_fmaf(RLF(rs0, 0), d0, A.a0);
    A.a1 = __builtin_fmaf(RLF(rs1, 0), d1, A.a1);
    A.a2 = __builtin_fmaf(RLF(rs2, 0), d2, A.a2);
    A.a3 = __builtin_fmaf(RLF(rs3, 0), d3, A.a3);
    A.a0 = __builtin_fmaf(RLF(rs0, 16), d4, A.a0);
    A.a1 = __builtin_fmaf(RLF(rs1, 16), d5, A.a1);
    A.a2 = __builtin_fmaf(RLF(rs2, 16), d6, A.a2);
    A.a3 = __builtin_fmaf(RLF(rs3, 16), d7, A.a3);
    A.a0 = __builtin_fmaf(RLF(rs0, 32), d8, A.a0);
    A.a1 = __builtin_fmaf(RLF(rs1, 32), d9, A.a1);
    A.a2 = __builtin_fmaf(RLF(rs2, 32), d10, A.a2);
    A.a3 = __builtin_fmaf(RLF(rs3, 32), d11, A.a3);
    A.a0 = __builtin_fmaf(RLF(rs0, 48), d12, A.a0);
    A.a1 = __builtin_fmaf(RLF(rs1, 48), d13, A.a1);
    A.a2 = __builtin_fmaf(RLF(rs2, 48), d14, A.a2);
    A.a3 = __builtin_fmaf(RLF(rs3, 48), d15, A.a3);
}

// ---------------------------------------------------------------------------
// CSR build. cnt packs {high16: #col-role incidences, low16: degree} via a
// single atomicAdd(1 + (role<<16)) -> sigma = deg - 2*ncol is h-independent
// and precomputed here, killing all ballot/sign machinery in fused_step.
// adj entry = other*256 (raw h-row byte offset, no role bit).
// ---------------------------------------------------------------------------
__global__ __launch_bounds__(256) void csr_count(const int* __restrict__ ei,
                                                 int* __restrict__ cnt,
                                                 unsigned short* __restrict__ rank16) {
    int i = blockIdx.x * 256 + threadIdx.x;
    if (i >= 2 * EE) return;
    int add = (i >= EE) ? 0x10001 : 1;
    int r = atomicAdd(&cnt[ei[i]], add);
    rank16[i] = (unsigned short)r;   // low16 of old value = rank
}

__global__ __launch_bounds__(256) void scanA(const int* __restrict__ cnt,
                                             int* __restrict__ offs,
                                             int* __restrict__ bsum) {
    __shared__ int tmp[256];
    int i = blockIdx.x * 256 + threadIdx.x;
    int v = (i < NN) ? (cnt[i] & 0xffff) : 0;
    tmp[threadIdx.x] = v;
    __syncthreads();
    int acc = v;
    for (int d = 1; d < 256; d <<= 1) {
        int t = (threadIdx.x >= d) ? tmp[threadIdx.x - d] : 0;
        __syncthreads();
        acc += t;
        tmp[threadIdx.x] = acc;
        __syncthreads();
    }
    if (i < NN) offs[i] = acc - v;
    if (threadIdx.x == 255) bsum[blockIdx.x] = acc;
}

__global__ __launch_bounds__(256) void scanB(int* __restrict__ bsum) {
    __shared__ int tmp[256];
    int v = (threadIdx.x < NB_SCAN) ? bsum[threadIdx.x] : 0;
    tmp[threadIdx.x] = v;
    __syncthreads();
    int acc = v;
    for (int d = 1; d < 256; d <<= 1) {
        int t = (threadIdx.x >= d) ? tmp[threadIdx.x - d] : 0;
        __syncthreads();
        acc += t;
        tmp[threadIdx.x] = acc;
        __syncthreads();
    }
    if (threadIdx.x < NB_SCAN) bsum[threadIdx.x] = acc - v;
}

__global__ __launch_bounds__(256) void scanC(int* __restrict__ offs,
                                             const int* __restrict__ bsum) {
    int i = blockIdx.x * 256 + threadIdx.x;
    if (i < NN) offs[i] += bsum[blockIdx.x];
}

__global__ __launch_bounds__(256) void csr_fill(const int* __restrict__ ei,
                                                const int* __restrict__ offs,
                                                const unsigned short* __restrict__ rank16,
                                                int* __restrict__ adj) {
    int i = blockIdx.x * 256 + threadIdx.x;
    if (i >= 2 * EE) return;
    int node  = ei[i];
    int other = (i >= EE) ? ei[i - EE] : ei[i + EE];
    adj[offs[node] + (int)rank16[i]] = other << 8;
}

// ---------------------------------------------------------------------------
// G = W @ W^T  (64x64). One block.
// ---------------------------------------------------------------------------
__global__ __launch_bounds__(256) void make_G(const float* __restrict__ W,
                                              float* __restrict__ G) {
    __shared__ float Ws[64 * 64];
    for (int t = threadIdx.x; t < 64 * 64; t += 256) Ws[t] = W[t];
    __syncthreads();
    for (int t = threadIdx.x; t < 64 * 64; t += 256) {
        int i = t >> 6, j = t & 63;
        float acc = 0.f;
#pragma unroll 8
        for (int k = 0; k < 64; ++k) acc += Ws[i * 64 + k] * Ws[j * 64 + k];
        G[t] = acc;
    }
}

// ---------------------------------------------------------------------------
// extractor: xh = x@We^T + be ; h0 = KTANH*(xh@U^T + bU) ; xU = (xh@U^T+bU)/nf
// ---------------------------------------------------------------------------
__global__ __launch_bounds__(256) void extractor(
        const float* __restrict__ x, const float* __restrict__ nf,
        const float* __restrict__ We, const float* __restrict__ be,
        const float* __restrict__ U,  const float* __restrict__ bU,
        float* __restrict__ xh, float* __restrict__ xU, float* __restrict__ h0) {
    __shared__ float WeT[INC * HH];
    __shared__ float UT[HH * HH];
    __shared__ float beS[HH], bUS[HH];
    __shared__ float xs[4][INC];
    __shared__ float xhs[4][HH];

    for (int t = threadIdx.x; t < INC * HH; t += 256) {
        int j = t >> 7, k = t & 127;
        WeT[k * 64 + j] = We[t];
    }
    for (int t = threadIdx.x; t < HH * HH; t += 256) {
        int j = t >> 6, k = t & 63;
        UT[k * 64 + j] = U[t];
    }
    if (threadIdx.x < 64) { beS[threadIdx.x] = be[threadIdx.x]; bUS[threadIdx.x] = bU[threadIdx.x]; }
    __syncthreads();

    int lane = threadIdx.x & 63;
    int wv   = threadIdx.x >> 6;

    for (int n0 = blockIdx.x * 4; n0 < NN; n0 += gridDim.x * 4) {
        int n = n0 + wv;
        bool valid = n < NN;
        if (valid) {
            xs[wv][lane]      = x[(size_t)n * INC + lane];
            xs[wv][lane + 64] = x[(size_t)n * INC + lane + 64];
        }
        __syncthreads();
        float acc = beS[lane];
        if (valid) {
#pragma unroll 8
            for (int k = 0; k < INC; ++k) acc += xs[wv][k] * WeT[k * 64 + lane];
            xh[n * 64 + lane] = acc;
            xhs[wv][lane] = acc;
        }
        __syncthreads();
        if (valid) {
            float acc2 = bUS[lane];
#pragma unroll 8
            for (int k = 0; k < HH; ++k) acc2 += xhs[wv][k] * UT[k * 64 + lane];
            h0[n * 64 + lane] = KTANH * acc2;
            xU[n * 64 + lane] = acc2 / nf[n];
        }
        __syncthreads();
    }
}

// ---------------------------------------------------------------------------
// fused step v12 (R18): tr-read LDS tiles (fixed addr), packed f16 writes,
// precomputed sigma, per-node cs combine. Control flow identical to R15.
// ---------------------------------------------------------------------------
#define HV(P) P##0, P##1, P##2, P##3, P##4, P##5, P##6, P##7,                 \
              P##8, P##9, P##10, P##11, P##12, P##13, P##14, P##15

#define G16(P, EV, J)                                                          \
    do {                                                                       \
        P##0  = GATH(RL(EV, (J) + 0));  P##1  = GATH(RL(EV, (J) + 1));         \
        P##2  = GATH(RL(EV, (J) + 2));  P##3  = GATH(RL(EV, (J) + 3));         \
        P##4  = GATH(RL(EV, (J) + 4));  P##5  = GATH(RL(EV, (J) + 5));         \
        P##6  = GATH(RL(EV, (J) + 6));  P##7  = GATH(RL(EV, (J) + 7));         \
        P##8  = GATH(RL(EV, (J) + 8));  P##9  = GATH(RL(EV, (J) + 9));         \
        P##10 = GATH(RL(EV, (J) + 10)); P##11 = GATH(RL(EV, (J) + 11));        \
        P##12 = GATH(RL(EV, (J) + 12)); P##13 = GATH(RL(EV, (J) + 13));        \
        P##14 = GATH(RL(EV, (J) + 14)); P##15 = GATH(RL(EV, (J) + 15));        \
    } while (0)

#define NEXTPREF(P)                                                            \
    do {                                                                       \
        if (morechunk)      { G16(P, evB, 0); }                                \
        else if (morenode)  { G16(P, evN, 0); }                                \
    } while (0)

__global__ __launch_bounds__(256) void fused_step(
        const int* __restrict__ adj, const int* __restrict__ offs,
        const int* __restrict__ cnt,
        const float* __restrict__ hcur, float* __restrict__ hnxt,
        const float* __restrict__ nf, const float* __restrict__ gamma,
        const float* __restrict__ beta, const float* __restrict__ Gm,
        const float* __restrict__ xU,
        float* __restrict__ y, float* __restrict__ s, int first, int last) {
    __shared__ float Gs[64 * 64];
    __shared__ __align__(16) _Float16 dt[4][2048];
    for (int t = threadIdx.x; t < 64 * 64; t += 256) Gs[t] = Gm[t];
    __syncthreads();

    const int lane = threadIdx.x & 63, wv = threadIdx.x >> 6;
    const float g = gamma[lane], b = beta[lane];

    v4i_t hsr;
    {
        unsigned long long up = (unsigned long long)(uintptr_t)hcur;
        hsr.x = (int)(unsigned)(up & 0xffffffffull);
        hsr.y = (int)(unsigned)(up >> 32);
        hsr.z = NN * HH * 4;
        hsr.w = 0x00020000;
    }
    const int lane4 = lane << 2;
#define GATH(e) llvm_amdgcn_raw_buffer_load_fp32(hsr, lane4, (e), 0)
#define RL(v, i) __builtin_amdgcn_readlane((v), (i))

    _Float16* tb = &dt[wv][0];
    char* wp = (char*)tb + lane * 32;                       // write row base
    const unsigned tbb = (unsigned)(uintptr_t)tb;           // LDS byte offset
    // TR base: group g=(l>>4) at feature-block 2g (g*256B); lane-in-group
    // i=(l&15) loads its own 8B chunk at i*8.  (R6 bug: i*2.)
    const int trv = (int)(tbb + ((lane >> 4) << 8) + ((lane & 15) << 3));
    const h8 ones = {(_Float16)1.f, (_Float16)1.f, (_Float16)1.f, (_Float16)1.f,
                     (_Float16)1.f, (_Float16)1.f, (_Float16)1.f, (_Float16)1.f};

    const int NW = 2048 * 4;
    int n = blockIdx.x * 4 + wv;       // NW < NN so always valid
    int cP   = __builtin_amdgcn_readfirstlane(cnt[n]);
    int base = __builtin_amdgcn_readfirstlane(offs[n]);
    int deg  = cP & 0xffff;
    int sgm  = deg - 2 * ((int)((unsigned)cP >> 16));
    int ev   = adj[base + lane];
    float hn = hcur[(size_t)n * 64 + lane];
    float hA0, hA1, hA2, hA3, hA4, hA5, hA6, hA7;
    float hA8, hA9, hA10, hA11, hA12, hA13, hA14, hA15;
    float hB0, hB1, hB2, hB3, hB4, hB5, hB6, hB7;
    float hB8, hB9, hB10, hB11, hB12, hB13, hB14, hB15;
    G16(hA, ev, 0);

    for (;;) {
        const int nxt = n + NW;
        const bool morenode = nxt < NN;
        int baseN = 0, cN = 0, evN = 0;
        float hnN = 0.f;
        if (morenode) {
            baseN = __builtin_amdgcn_readfirstlane(offs[nxt]);
            cN    = __builtin_amdgcn_readfirstlane(cnt[nxt]);
            evN   = adj[baseN + lane];
            hnN   = hcur[(size_t)nxt * 64 + lane];
        }
        TileAcc A = {0.f, 0.f, 0.f, 0.f, 0.f};

        if (deg > 0) {
            int cbase = 0;
            for (;;) {
                int nE = deg - cbase;
                if (nE > 64) nE = 64;
                const bool morechunk = (cbase + 64 < deg);
                int evB = 0;
                if (morechunk) evB = adj[base + cbase + 64 + lane];

                if (nE == 64) {
                    G16(hB, ev, 16);
                    tile16<false>(A, hn, 0, HV(hA), wp, trv, ones);
                    G16(hA, ev, 32);
                    tile16<false>(A, hn, 0, HV(hB), wp, trv, ones);
                    G16(hB, ev, 48);
                    tile16<false>(A, hn, 0, HV(hA), wp, trv, ones);
                    NEXTPREF(hA);
                    tile16<false>(A, hn, 0, HV(hB), wp, trv, ones);
                } else {
                    const int nt = (nE + 15) >> 4;
                    if (nt > 1) { G16(hB, ev, 16); } else { NEXTPREF(hB); }
                    tile16<true>(A, hn, nE, HV(hA), wp, trv, ones);
                    if (nt > 1) {
                        if (nt > 2) { G16(hA, ev, 32); } else { NEXTPREF(hA); }
                        tile16<true>(A, hn, nE - 16, HV(hB), wp, trv, ones);
                        if (nt > 2) {
                            if (nt > 3) { G16(hB, ev, 48); } else { NEXTPREF(hB); }
                            tile16<true>(A, hn, nE - 32, HV(hA), wp, trv, ones);
                            if (nt > 3) {
                                NEXTPREF(hA);
                                tile16<true>(A, hn, nE - 48, HV(hB), wp, trv, ones);
                            }
                        }
                    }
                    if (nt & 1) {
                        hA0 = hB0;  hA1 = hB1;  hA2 = hB2;  hA3 = hB3;
                        hA4 = hB4;  hA5 = hB5;  hA6 = hB6;  hA7 = hB7;
                        hA8 = hB8;  hA9 = hB9;  hA10 = hB10; hA11 = hB11;
                        hA12 = hB12; hA13 = hB13; hA14 = hB14; hA15 = hB15;
                    }
                }
                if (!morechunk) break;
                ev = evB;
                cbase += 64;
            }
        } else {
            if (morenode) { G16(hA, evN, 0); }
        }

        // ---- epilogue: combine per-lane cs partials (row-uniform) once
        float scp = A.sc;
        asm volatile(
            "s_nop 1\n\t"
            "v_add_f32_dpp %0, %0, %0 row_bcast:15 row_mask:0xa bank_mask:0xf bound_ctrl:0\n\t"
            "s_nop 1\n\t"
            "v_add_f32_dpp %0, %0, %0 row_bcast:31 row_mask:0xc bank_mask:0xf bound_ctrl:0"
            : "+v"(scp));
        const float accM = ((A.a0 + A.a1) + (A.a2 + A.a3)) - rl63(scp);
        const float nfn = nf[n];
        const float av  = nfn * __builtin_fmaf(g, accM, b * (float)sgm);

        float p = 0.f;
        const int avi = __float_as_int(av);
#pragma unroll
        for (int k = 0; k < 64; ++k) {
            float ak = __int_as_float(RL(avi, k));
            p = __builtin_fmaf(ak, Gs[k * 64 + lane], p);
        }

        float yprev = 0.f, sprev = 0.f;
        if (!first) {
            yprev = y[n * 64 + lane];
            sprev = s[n * 64 + lane];
        }
        const float yv = -ALPHA * p + (1.0f - ALPHA) * yprev;
        y[n * 64 + lane] = yv;
        s[n * 64 + lane] = (1.0f - ALPHA) * sprev + av;
        if (!last) hnxt[n * 64 + lane] = KTANH * (nfn * (yv + xU[n * 64 + lane]));

        if (!morenode) break;
        n = nxt; base = baseN;
        deg = cN & 0xffff;
        sgm = deg - 2 * ((int)((unsigned)cN >> 16));
        ev = evN; hn = hnN;
    }
#undef GATH
#undef RL
}

// ---------------------------------------------------------------------------
// final: z = -alpha*(s@W) ; zf = nf*z + xh ; out = zf@Wlast^T + blast
// ---------------------------------------------------------------------------
__global__ __launch_bounds__(256) void final_out(
        const float* __restrict__ s, const float* __restrict__ xh,
        const float* __restrict__ nf, const float* __restrict__ W,
        const float* __restrict__ Wlast, const float* __restrict__ blast,
        float* __restrict__ out) {
    __shared__ float Ws[64 * 64];
    __shared__ float WlT[64 * OUTC];
    __shared__ float blS[OUTC];
    __shared__ float ss[4][64];
    __shared__ float zfs[4][64];
    for (int t = threadIdx.x; t < 64 * 64; t += 256) Ws[t] = W[t];
    for (int t = threadIdx.x; t < OUTC * 64; t += 256) {
        int o = t >> 6, j = t & 63;
        WlT[j * OUTC + o] = Wlast[t];
    }
    if (threadIdx.x < OUTC) blS[threadIdx.x] = blast[threadIdx.x];
    __syncthreads();
    int lane = threadIdx.x & 63, wv = threadIdx.x >> 6;
    for (int n0 = blockIdx.x * 4; n0 < NN; n0 += gridDim.x * 4) {
        int n = n0 + wv;
        if (n < NN) ss[wv][lane] = s[n * 64 + lane];
        __syncthreads();
        if (n < NN) {
            float z = 0.f;
#pragma unroll 8
            for (int k = 0; k < 64; ++k) z += ss[wv][k] * Ws[k * 64 + lane];
            z *= -ALPHA;
            zfs[wv][lane] = nf[n] * z + xh[n * 64 + lane];
        }
        __syncthreads();
        if (n < NN && lane < OUTC) {
            float acc = blS[lane];
#pragma unroll 8
            for (int j = 0; j < 64; ++j) acc += zfs[wv][j] * WlT[j * OUTC + lane];
            out[n * OUTC + lane] = acc;
        }
        __syncthreads();
    }
}

// ---------------------------------------------------------------------------
extern "C" void kernel_launch(void* const* d_in, const int* in_sizes, int n_in,
                              void* d_out, int out_size, void* d_ws, size_t ws_size,
                              hipStream_t stream) {
    const float* x     = (const float*)d_in[0];
    const int*   ei    = (const int*)  d_in[1];
    const float* nf    = (const float*)d_in[2];
    const float* We    = (const float*)d_in[3];
    const float* be    = (const float*)d_in[4];
    const float* W     = (const float*)d_in[5];
    const float* U     = (const float*)d_in[6];
    const float* bU    = (const float*)d_in[7];
    const float* gamma = (const float*)d_in[8];
    const float* beta  = (const float*)d_in[9];
    const float* Wlast = (const float*)d_in[10];
    const float* blast = (const float*)d_in[11];
    float* out = (float*)d_out;

    char* ws = (char*)d_ws;
    size_t off = 0;
    const size_t NH = (size_t)NN * HH * sizeof(float);
    int*   adj    = (int*)(ws + off);            off += (size_t)2 * EE * sizeof(int) + 256;
    unsigned short* rank16 = (unsigned short*)(ws + off);
                                                 off += (size_t)2 * EE * sizeof(unsigned short);
    int*   offs   = (int*)(ws + off);            off += (size_t)NN * sizeof(int);
    int*   cnt    = (int*)(ws + off);            off += (size_t)NN * sizeof(int);
    int*   bsum   = (int*)(ws + off);            off += 256 * sizeof(int);
    float* xh     = (float*)(ws + off);          off += NH;
    float* xU     = (float*)(ws + off);          off += NH;
    float* h0     = (float*)(ws + off);          off += NH;
    float* h1     = (float*)(ws + off);          off += NH;
    float* y      = (float*)(ws + off);          off += NH;
    float* s      = (float*)(ws + off);          off += NH;
    float* G      = (float*)(ws + off);          off += (size_t)HH * HH * sizeof(float);

    (void)hipMemsetAsync(cnt, 0, (size_t)NN * sizeof(int), stream);
    // y/s zero-init folded into fused_step (first=1)

    csr_count<<<(2 * EE + 255) / 256, 256, 0, stream>>>(ei, cnt, rank16);
    scanA<<<NB_SCAN, 256, 0, stream>>>(cnt, offs, bsum);
    scanB<<<1, 256, 0, stream>>>(bsum);
    scanC<<<NB_SCAN, 256, 0, stream>>>(offs, bsum);
    csr_fill<<<(2 * EE + 255) / 256, 256, 0, stream>>>(ei, offs, rank16, adj);

    make_G<<<1, 256, 0, stream>>>(W, G);
    extractor<<<2048, 256, 0, stream>>>(x, nf, We, be, U, bU, xh, xU, h0);

    float* hc = h0;
    float* hn = h1;
    for (int t = 0; t < 4; ++t) {
        fused_step<<<2048, 256, 0, stream>>>(adj, offs, cnt, hc, hn, nf,
                                             gamma, beta, G, xU, y, s,
                                             t == 0, t == 3);
        float* tmp = hc; hc = hn; hn = tmp;
    }
    final_out<<<2048, 256, 0, stream>>>(s, xh, nf, W, Wlast, blast, out);
}